// Round 1
// baseline (1853.737 us; speedup 1.0000x reference)
//
#include <hip/hip_runtime.h>
#include <hip/hip_bf16.h>

#define NTRAIN 100000
#define NBIT   64
#define NCLASS 100
#define NBATCH 128
#define NW     1563   /* ceil(100000/64) */
#define NWP    1568   /* padded stride   */
#define NP1    100001.0f
#define ETA_MU 55.0f

#define NBLK   391    /* ceil(100000/256) */

// ---------------- workspace layout (bytes) ----------------
#define OFF_BMASK   0u                       /* u64[100000]      800000 */
#define OFF_PLANES  800000u                  /* u64[64][1568]    802816 */
#define OFF_CMASK   1602816u                 /* u64[100][1568]  1254400 */
#define OFF_LABELY  2857216u                 /* int[100000]      400000 */
#define OFF_OVR     3257216u                 /* int[100000]      400000 */
#define OFF_YLAB    3657216u                 /* int[128]            512 */
#define OFF_CCOUNT  3657728u                 /* int[100]            512 */
#define OFF_A       3658240u                 /* f32[64][64]       16384 */
#define OFF_RHS     3674624u                 /* f32[64][100]      25600 */
#define OFF_W       3700224u                 /* f32[64][100]      25600 */
#define OFF_G       3725824u                 /* f32[64][64]       16384 */
#define OFF_PART    3742208u                 /* f32[391] -> 2048        */
#define OFF_CLREG   3744256u                 /* f32[2]                  */

__device__ __forceinline__ float blk_reduce_sum(float v, float* sbuf) {
    int tid = threadIdx.x;
    for (int off = 32; off > 0; off >>= 1) v += __shfl_down(v, off, 64);
    __syncthreads();
    if ((tid & 63) == 0) sbuf[tid >> 6] = v;
    __syncthreads();
    float t = 0.f;
    if (tid == 0) {
        int nw = (int)(blockDim.x >> 6);
        for (int q = 0; q < nw; ++q) t += sbuf[q];
    }
    return t;   // valid on tid 0 only
}

// label of every training column from the (one-hot-per-column) Y
__global__ __launch_bounds__(256) void k_labels(const float* __restrict__ Y,
                                                int* __restrict__ labelY) {
    int j = blockIdx.x * 256 + threadIdx.x;
    if (j >= NTRAIN) return;
    int lab = 0;
    for (int r = 0; r < NCLASS; ++r)
        if (Y[r * NTRAIN + j] > 0.5f) lab = r;
    labelY[j] = lab;
}

// batch labels + sequential (last-wins) scatter of labelY / override table
__global__ void k_scatter(const float* __restrict__ y, const int* __restrict__ ind,
                          int* __restrict__ labelY, int* __restrict__ ovr,
                          int* __restrict__ ylab) {
    __shared__ int cls[NBATCH], idx[NBATCH];
    int k = threadIdx.x;
    if (k < NBATCH) {
        int c = 0;
        for (int r = 0; r < NCLASS; ++r)
            if (y[k * NCLASS + r] > 0.5f) c = r;
        cls[k] = c; idx[k] = ind[k]; ylab[k] = c;
    }
    __syncthreads();
    if (k == 0) {
        for (int q = 0; q < NBATCH; ++q) {
            labelY[idx[q]] = cls[q];
            ovr[idx[q]] = q + 1;
        }
    }
}

// B (f32 +-1, row-major [64][100000]) -> per-column 64-bit sign masks
__global__ __launch_bounds__(256) void k_masks(const float* __restrict__ B,
                                               unsigned long long* __restrict__ Bmask) {
    int j = blockIdx.x * 256 + threadIdx.x;
    if (j >= NTRAIN) return;
    unsigned long long m = 0ull;
    #pragma unroll
    for (int i = 0; i < NBIT; ++i)
        if (B[i * NTRAIN + j] > 0.0f) m |= (1ull << i);
    Bmask[j] = m;
}

// per-class column bitmasks (atomicOr is order-independent -> deterministic)
__global__ __launch_bounds__(256) void k_cmask(const int* __restrict__ labelY,
                                               unsigned long long* __restrict__ cmask) {
    int j = blockIdx.x * 256 + threadIdx.x;
    if (j >= NTRAIN) return;
    int c = labelY[j];
    atomicOr(&cmask[(size_t)c * NWP + (j >> 6)], 1ull << (j & 63));
}

__global__ void k_counts(const unsigned long long* __restrict__ cmask,
                         int* __restrict__ ccount) {
    int c = threadIdx.x;
    if (c >= NCLASS) return;
    int cnt = 0;
    for (int w = 0; w < NW; ++w) cnt += __popcll(cmask[(size_t)c * NWP + w]);
    ccount[c] = cnt;
}

// column-masks -> row bitplanes (64x64 bit transpose via ballot)
__global__ __launch_bounds__(256) void k_transpose(const unsigned long long* __restrict__ Bmask,
                                                   unsigned long long* __restrict__ planes) {
    int gid = blockIdx.x * 256 + threadIdx.x;
    int w = gid >> 6, lane = threadIdx.x & 63;
    if (w >= NW) return;
    int j = w * 64 + lane;
    unsigned long long m = (j < NTRAIN) ? Bmask[j] : 0ull;
    unsigned long long acc = 0ull;
    #pragma unroll
    for (int i = 0; i < 64; ++i) {
        unsigned long long bal = __ballot((m >> i) & 1ull);
        if (lane == i) acc = bal;
    }
    planes[(size_t)lane * NWP + w] = acc;
}

// A = (B B^T - N I)/(N+1)  (zero diag, exact ints via xor-popcount)
// RHS = B Y^T via and-popcount against class masks
__global__ __launch_bounds__(256) void k_bbt_byt(const unsigned long long* __restrict__ planes,
                                                 const unsigned long long* __restrict__ cmask,
                                                 const int* __restrict__ ccount,
                                                 float* __restrict__ A, float* __restrict__ RHS) {
    __shared__ unsigned long long pk[NW];
    __shared__ int partA[64][4];
    __shared__ int partB[100][4];
    int k = blockIdx.x, tid = threadIdx.x;
    for (int w = tid; w < NW; w += 256) pk[w] = planes[(size_t)k * NWP + w];
    __syncthreads();
    {
        int l = tid >> 2, ch = tid & 3;
        int w0 = ch * 391, w1 = w0 + 391; if (w1 > NW) w1 = NW;
        const unsigned long long* pl = planes + (size_t)l * NWP;
        int cnt = 0;
        for (int w = w0; w < w1; ++w) cnt += __popcll(pk[w] ^ pl[w]);
        partA[l][ch] = cnt;
    }
    for (int t2 = tid; t2 < 400; t2 += 256) {
        int c = t2 >> 2, ch = t2 & 3;
        int w0 = ch * 391, w1 = w0 + 391; if (w1 > NW) w1 = NW;
        const unsigned long long* cm = cmask + (size_t)c * NWP;
        int cnt = 0;
        for (int w = w0; w < w1; ++w) cnt += __popcll(pk[w] & cm[w]);
        partB[c][ch] = cnt;
    }
    __syncthreads();
    if (tid < 64) {
        int cnt = partA[tid][0] + partA[tid][1] + partA[tid][2] + partA[tid][3];
        float v = (float)(NTRAIN - 2 * cnt) * (1.0f / NP1);
        A[k * 64 + tid] = (tid == k) ? 0.0f : v;
    }
    if (tid >= 64 && tid < 64 + NCLASS) {
        int c = tid - 64;
        int cnt = partB[c][0] + partB[c][1] + partB[c][2] + partB[c][3];
        RHS[k * NCLASS + c] = (float)(2 * cnt - ccount[c]);
    }
}

// inv(M) = (I - A + A^2 - ...)/(N+1) via Horner (cond(M)~1.01), then W, G=WW^T
__global__ __launch_bounds__(256) void k_solve(const float* __restrict__ A_g,
                                               const float* __restrict__ RHS_g,
                                               float* __restrict__ W_g,
                                               float* __restrict__ G_g) {
    __shared__ float As[4096];
    __shared__ float T[4096], T2[4096];
    __shared__ float Ws[6400];
    int tid = threadIdx.x;
    for (int e = tid; e < 4096; e += 256) {
        As[e] = A_g[e];
        T[e] = ((e >> 6) == (e & 63)) ? 1.f : 0.f;
    }
    __syncthreads();
    for (int it = 0; it < 8; ++it) {
        float* Tin  = (it & 1) ? T2 : T;
        float* Tout = (it & 1) ? T  : T2;
        for (int e = tid; e < 4096; e += 256) {
            int r = e >> 6, cc = e & 63;
            float a0 = 0, a1 = 0, a2 = 0, a3 = 0;
            #pragma unroll 8
            for (int k = 0; k < 64; k += 4) {
                a0 = fmaf(As[r * 64 + k],     Tin[k * 64 + cc],       a0);
                a1 = fmaf(As[r * 64 + k + 1], Tin[(k + 1) * 64 + cc], a1);
                a2 = fmaf(As[r * 64 + k + 2], Tin[(k + 2) * 64 + cc], a2);
                a3 = fmaf(As[r * 64 + k + 3], Tin[(k + 3) * 64 + cc], a3);
            }
            Tout[e] = ((r == cc) ? 1.f : 0.f) - ((a0 + a1) + (a2 + a3));
        }
        __syncthreads();
    }
    // 8 iterations: final result lives in T
    for (int e = tid; e < 6400; e += 256) {
        int i = e / 100, c = e % 100;
        float a0 = 0, a1 = 0, a2 = 0, a3 = 0;
        #pragma unroll 8
        for (int k = 0; k < 64; k += 4) {
            a0 = fmaf(T[i * 64 + k],     RHS_g[k * 100 + c],       a0);
            a1 = fmaf(T[i * 64 + k + 1], RHS_g[(k + 1) * 100 + c], a1);
            a2 = fmaf(T[i * 64 + k + 2], RHS_g[(k + 2) * 100 + c], a2);
            a3 = fmaf(T[i * 64 + k + 3], RHS_g[(k + 3) * 100 + c], a3);
        }
        float w = ((a0 + a1) + (a2 + a3)) * (1.0f / NP1);
        Ws[e] = w; W_g[e] = w;
    }
    __syncthreads();
    for (int e = tid; e < 4096; e += 256) {
        int k = e >> 6, l = e & 63;
        float a0 = 0, a1 = 0;
        #pragma unroll 10
        for (int c = 0; c < 100; c += 2) {
            a0 = fmaf(Ws[k * 100 + c],     Ws[l * 100 + c],     a0);
            a1 = fmaf(Ws[k * 100 + c + 1], Ws[l * 100 + c + 1], a1);
        }
        G_g[e] = a0 + a1;
    }
}

// one DCC pass: thread-per-column, b in 64 VGPRs, fully unrolled 64x64 FMA
__global__ __launch_bounds__(256) void k_scan(unsigned long long* __restrict__ Bmask,
                                              const int* __restrict__ labelY,
                                              const int* __restrict__ ovr,
                                              const float* __restrict__ Wg,
                                              const float* __restrict__ Gg,
                                              const float* __restrict__ U,
                                              const float* __restrict__ u) {
    int j = blockIdx.x * 256 + threadIdx.x;
    if (j >= NTRAIN) return;
    unsigned long long m = Bmask[j];
    int c = labelY[j];
    int ov = ovr[j];
    const float* up; int ustr;
    if (ov) { up = u + (ov - 1) * NBIT; ustr = 1; }
    else    { up = U + j;               ustr = NTRAIN; }
    float s[NBIT];
    #pragma unroll
    for (int i = 0; i < NBIT; ++i) s[i] = ((m >> i) & 1ull) ? 1.0f : -1.0f;
    #pragma unroll
    for (int i = 0; i < NBIT; ++i) {
        float p = Wg[i * NCLASS + c] + ETA_MU * up[i * ustr];
        const float* Gi = Gg + i * 64;
        float f0 = 0, f1 = 0, f2 = 0, f3 = 0;
        #pragma unroll
        for (int k = 0; k < NBIT; k += 4) {
            if (k     != i) f0 = fmaf(Gi[k],     s[k],     f0);
            if (k + 1 != i) f1 = fmaf(Gi[k + 1], s[k + 1], f1);
            if (k + 2 != i) f2 = fmaf(Gi[k + 2], s[k + 2], f2);
            if (k + 3 != i) f3 = fmaf(Gi[k + 3], s[k + 3], f3);
        }
        float f = (f0 + f1) + (f2 + f3);
        s[i] = ((p - f) > 0.0f) ? 1.0f : -1.0f;
    }
    unsigned long long mo = 0ull;
    #pragma unroll
    for (int i = 0; i < NBIT; ++i) if (s[i] > 0.0f) mo |= (1ull << i);
    Bmask[j] = mo;
}

// likelihood: thread-per-column; U column in regs, u rows via uniform scalar loads
__global__ __launch_bounds__(256) void k_lik(const float* __restrict__ U,
                                             const float* __restrict__ u,
                                             const int* __restrict__ labelY,
                                             const int* __restrict__ ovr,
                                             const int* __restrict__ ylab,
                                             float* __restrict__ partials) {
    __shared__ float sbuf[8];
    int j = blockIdx.x * 256 + threadIdx.x;
    float acc = 0.0f;
    if (j < NTRAIN) {
        int ov = ovr[j];
        const float* up; int ustr;
        if (ov) { up = u + (ov - 1) * NBIT; ustr = 1; }
        else    { up = U + j;               ustr = NTRAIN; }
        float Ucol[NBIT];
        #pragma unroll
        for (int i = 0; i < NBIT; ++i) Ucol[i] = up[i * ustr];
        int cj = labelY[j];
        for (int b = 0; b < NBATCH; ++b) {
            const float* ub = u + b * NBIT;
            float a0 = 0, a1 = 0, a2 = 0, a3 = 0;
            #pragma unroll
            for (int i = 0; i < NBIT; i += 4) {
                a0 = fmaf(ub[i],     Ucol[i],     a0);
                a1 = fmaf(ub[i + 1], Ucol[i + 1], a1);
                a2 = fmaf(ub[i + 2], Ucol[i + 2], a2);
                a3 = fmaf(ub[i + 3], Ucol[i + 3], a3);
            }
            float ip = 0.5f * ((a0 + a1) + (a2 + a3));
            float aip = fabsf(ip);
            float t = __logf(1.0f + __expf(-aip)) + fmaxf(ip, 0.0f);
            if (ylab[b] == cj) t -= ip;
            acc += t;
        }
    }
    float tot = blk_reduce_sum(acc, sbuf);
    if (threadIdx.x == 0) partials[blockIdx.x] = tot;
}

__global__ void k_clreg(const float* __restrict__ Wg,
                        const unsigned long long* __restrict__ Bmask,
                        const int* __restrict__ ind,
                        const float* __restrict__ y,
                        float* __restrict__ clreg) {
    __shared__ float sbuf[8];
    __shared__ unsigned long long mB[NBATCH];
    int tid = threadIdx.x;
    if (tid < NBATCH) mB[tid] = Bmask[ind[tid]];
    __syncthreads();
    float accCl = 0.f;
    for (int e = tid; e < NCLASS * NBATCH; e += 256) {
        int b = e & 127, c = e >> 7;
        unsigned long long m = mB[b];
        float d0 = 0.f;
        #pragma unroll
        for (int i = 0; i < NBIT; ++i) {
            float w = Wg[i * NCLASS + c];
            d0 += ((m >> i) & 1ull) ? w : -w;
        }
        float diff = y[b * NCLASS + c] - d0;
        accCl = fmaf(diff, diff, accCl);
    }
    float accRg = 0.f;
    for (int e = tid; e < NBIT * NCLASS; e += 256) {
        float w = Wg[e];
        accRg = fmaf(w, w, accRg);
    }
    float clS = blk_reduce_sum(accCl, sbuf);
    float rgS = blk_reduce_sum(accRg, sbuf);
    if (tid == 0) { clreg[0] = clS; clreg[1] = rgS; }
}

__global__ void k_final(const float* __restrict__ partials,
                        const float* __restrict__ clreg,
                        float* __restrict__ out) {
    __shared__ float sbuf[8];
    int tid = threadIdx.x;
    float a = 0.f;
    for (int i = tid; i < NBLK; i += 256) a += partials[i];
    float lik = blk_reduce_sum(a, sbuf);
    if (tid == 0) {
        out[0] = lik * (1.0f / ((float)NBATCH * (float)NTRAIN))
               + clreg[0] * (1.0f / (float)(NCLASS * NBATCH))
               + clreg[1] * (1.0f / (float)(NBIT * NCLASS));
    }
}

extern "C" void kernel_launch(void* const* d_in, const int* in_sizes, int n_in,
                              void* d_out, int out_size, void* d_ws, size_t ws_size,
                              hipStream_t stream) {
    const float* u   = (const float*)d_in[0];
    const float* y   = (const float*)d_in[1];
    const float* U   = (const float*)d_in[2];
    const float* B   = (const float*)d_in[3];
    const float* Y   = (const float*)d_in[4];
    const int*   ind = (const int*)d_in[5];

    char* ws = (char*)d_ws;
    unsigned long long* Bmask  = (unsigned long long*)(ws + OFF_BMASK);
    unsigned long long* planes = (unsigned long long*)(ws + OFF_PLANES);
    unsigned long long* cmask  = (unsigned long long*)(ws + OFF_CMASK);
    int*   labelY = (int*)(ws + OFF_LABELY);
    int*   ovr    = (int*)(ws + OFF_OVR);
    int*   ylab   = (int*)(ws + OFF_YLAB);
    int*   ccount = (int*)(ws + OFF_CCOUNT);
    float* A      = (float*)(ws + OFF_A);
    float* RHS    = (float*)(ws + OFF_RHS);
    float* W      = (float*)(ws + OFF_W);
    float* G      = (float*)(ws + OFF_G);
    float* part   = (float*)(ws + OFF_PART);
    float* clreg  = (float*)(ws + OFF_CLREG);

    hipMemsetAsync(ovr,   0, NTRAIN * sizeof(int), stream);
    hipMemsetAsync(cmask, 0, (size_t)NCLASS * NWP * sizeof(unsigned long long), stream);

    k_labels <<<NBLK, 256, 0, stream>>>(Y, labelY);
    k_scatter<<<1, 128, 0, stream>>>(y, ind, labelY, ovr, ylab);
    k_masks  <<<NBLK, 256, 0, stream>>>(B, Bmask);
    k_cmask  <<<NBLK, 256, 0, stream>>>(labelY, cmask);
    k_counts <<<1, 128, 0, stream>>>(cmask, ccount);

    for (int pass = 0; pass < 3; ++pass) {
        k_transpose<<<NBLK, 256, 0, stream>>>(Bmask, planes);
        k_bbt_byt  <<<64, 256, 0, stream>>>(planes, cmask, ccount, A, RHS);
        k_solve    <<<1, 256, 0, stream>>>(A, RHS, W, G);
        k_scan     <<<NBLK, 256, 0, stream>>>(Bmask, labelY, ovr, W, G, U, u);
    }

    k_lik  <<<NBLK, 256, 0, stream>>>(U, u, labelY, ovr, ylab, part);
    k_clreg<<<1, 256, 0, stream>>>(W, Bmask, ind, y, clreg);
    k_final<<<1, 256, 0, stream>>>(part, clreg, (float*)d_out);
}

// Round 2
// 1280.834 us; speedup vs baseline: 1.4473x; 1.4473x over previous
//
#include <hip/hip_runtime.h>
#include <hip/hip_bf16.h>

#define NTRAIN 100000
#define NBIT   64
#define NCLASS 100
#define NBATCH 128
#define NW     1563   /* ceil(100000/64) */
#define NWP    1568   /* padded stride   */
#define NP1    100001.0f
#define ETA_MU 55.0f

#define NBLK   391    /* ceil(100000/256) */

// ---------------- workspace layout (bytes) ----------------
#define OFF_BMASK   0u                       /* u64[100000]      800000 */
#define OFF_PLANES  800000u                  /* u64[64][1568]    802816 */
#define OFF_CMASK   1602816u                 /* u64[100][1568]  1254400 */
#define OFF_LABELY  2857216u                 /* int[100000]      400000 */
#define OFF_OVR     3257216u                 /* int[100000]      400000 */
#define OFF_YLAB    3657216u                 /* int[128]            512 */
#define OFF_CCOUNT  3657728u                 /* int[100]            512 */
#define OFF_A       3658240u                 /* f32[64][64]       16384 */
#define OFF_RHS     3674624u                 /* f32[64][100]      25600 */
#define OFF_W       3700224u                 /* f32[64][100]      25600 */
#define OFF_G       3725824u                 /* f32[64][64]       16384 */
#define OFF_PART    3742208u                 /* f32[391] -> 2048        */
#define OFF_CLREG   3744256u                 /* f32[2]                  */

__device__ __forceinline__ float blk_reduce_sum(float v, float* sbuf) {
    int tid = threadIdx.x;
    for (int off = 32; off > 0; off >>= 1) v += __shfl_down(v, off, 64);
    __syncthreads();
    if ((tid & 63) == 0) sbuf[tid >> 6] = v;
    __syncthreads();
    float t = 0.f;
    if (tid == 0) {
        int nw = (int)(blockDim.x >> 6);
        for (int q = 0; q < nw; ++q) t += sbuf[q];
    }
    return t;   // valid on tid 0 only
}

// fused: label of every training column + B sign-mask per column
__global__ __launch_bounds__(256) void k_prep(const float* __restrict__ Y,
                                              const float* __restrict__ B,
                                              int* __restrict__ labelY,
                                              unsigned long long* __restrict__ Bmask) {
    int j = blockIdx.x * 256 + threadIdx.x;
    if (j >= NTRAIN) return;
    int lab = 0;
    for (int r = 0; r < NCLASS; ++r)
        if (Y[r * NTRAIN + j] > 0.5f) lab = r;
    labelY[j] = lab;
    unsigned long long m = 0ull;
    #pragma unroll
    for (int i = 0; i < NBIT; ++i)
        if (B[i * NTRAIN + j] > 0.0f) m |= (1ull << i);
    Bmask[j] = m;
}

// batch labels + sequential (last-wins) scatter of labelY / override table
__global__ void k_scatter(const float* __restrict__ y, const int* __restrict__ ind,
                          int* __restrict__ labelY, int* __restrict__ ovr,
                          int* __restrict__ ylab) {
    __shared__ int cls[NBATCH], idx[NBATCH];
    int k = threadIdx.x;
    if (k < NBATCH) {
        int c = 0;
        for (int r = 0; r < NCLASS; ++r)
            if (y[k * NCLASS + r] > 0.5f) c = r;
        cls[k] = c; idx[k] = ind[k]; ylab[k] = c;
    }
    __syncthreads();
    if (k == 0) {
        for (int q = 0; q < NBATCH; ++q) {
            labelY[idx[q]] = cls[q];
            ovr[idx[q]] = q + 1;
        }
    }
}

// per-class column bitmasks (atomicOr is order-independent -> deterministic)
__global__ __launch_bounds__(256) void k_cmask(const int* __restrict__ labelY,
                                               unsigned long long* __restrict__ cmask) {
    int j = blockIdx.x * 256 + threadIdx.x;
    if (j >= NTRAIN) return;
    int c = labelY[j];
    atomicOr(&cmask[(size_t)c * NWP + (j >> 6)], 1ull << (j & 63));
}

__global__ void k_counts(const unsigned long long* __restrict__ cmask,
                         int* __restrict__ ccount) {
    int c = threadIdx.x;
    if (c >= NCLASS) return;
    int cnt = 0;
    for (int w = 0; w < NW; ++w) cnt += __popcll(cmask[(size_t)c * NWP + w]);
    ccount[c] = cnt;
}

// column-masks -> row bitplanes (64x64 bit transpose via ballot)
__global__ __launch_bounds__(256) void k_transpose(const unsigned long long* __restrict__ Bmask,
                                                   unsigned long long* __restrict__ planes) {
    int gid = blockIdx.x * 256 + threadIdx.x;
    int w = gid >> 6, lane = threadIdx.x & 63;
    if (w >= NW) return;
    int j = w * 64 + lane;
    unsigned long long m = (j < NTRAIN) ? Bmask[j] : 0ull;
    unsigned long long acc = 0ull;
    #pragma unroll
    for (int i = 0; i < 64; ++i) {
        unsigned long long bal = __ballot((m >> i) & 1ull);
        if (lane == i) acc = bal;
    }
    planes[(size_t)lane * NWP + w] = acc;
}

// A = (B B^T - N I)/(N+1)  (zero diag, exact ints via xor-popcount)
// RHS = B Y^T via and-popcount against class masks
__global__ __launch_bounds__(256) void k_bbt_byt(const unsigned long long* __restrict__ planes,
                                                 const unsigned long long* __restrict__ cmask,
                                                 const int* __restrict__ ccount,
                                                 float* __restrict__ A, float* __restrict__ RHS) {
    __shared__ unsigned long long pk[NW];
    __shared__ int partA[64][4];
    __shared__ int partB[100][4];
    int k = blockIdx.x, tid = threadIdx.x;
    for (int w = tid; w < NW; w += 256) pk[w] = planes[(size_t)k * NWP + w];
    __syncthreads();
    {
        int l = tid >> 2, ch = tid & 3;
        int w0 = ch * 391, w1 = w0 + 391; if (w1 > NW) w1 = NW;
        const unsigned long long* pl = planes + (size_t)l * NWP;
        int cnt = 0;
        for (int w = w0; w < w1; ++w) cnt += __popcll(pk[w] ^ pl[w]);
        partA[l][ch] = cnt;
    }
    for (int t2 = tid; t2 < 400; t2 += 256) {
        int c = t2 >> 2, ch = t2 & 3;
        int w0 = ch * 391, w1 = w0 + 391; if (w1 > NW) w1 = NW;
        const unsigned long long* cm = cmask + (size_t)c * NWP;
        int cnt = 0;
        for (int w = w0; w < w1; ++w) cnt += __popcll(pk[w] & cm[w]);
        partB[c][ch] = cnt;
    }
    __syncthreads();
    if (tid < 64) {
        int cnt = partA[tid][0] + partA[tid][1] + partA[tid][2] + partA[tid][3];
        float v = (float)(NTRAIN - 2 * cnt) * (1.0f / NP1);
        A[k * 64 + tid] = (tid == k) ? 0.0f : v;
    }
    if (tid >= 64 && tid < 64 + NCLASS) {
        int c = tid - 64;
        int cnt = partB[c][0] + partB[c][1] + partB[c][2] + partB[c][3];
        RHS[k * NCLASS + c] = (float)(2 * cnt - ccount[c]);
    }
}

// inv(M) = (I - A + A^2 - ...)/(N+1) via Horner (cond(M)~1.01), then W, G=WW^T
// G is written with a ZERO diagonal: k_scan's update excludes the i-th term,
// which is exactly "zero G[i][i]" (adding 0.0f*s_i is a bitwise no-op).
__global__ __launch_bounds__(256) void k_solve(const float* __restrict__ A_g,
                                               const float* __restrict__ RHS_g,
                                               float* __restrict__ W_g,
                                               float* __restrict__ G_g) {
    __shared__ float As[4096];
    __shared__ float T[4096], T2[4096];
    __shared__ float Ws[6400];
    int tid = threadIdx.x;
    for (int e = tid; e < 4096; e += 256) {
        As[e] = A_g[e];
        T[e] = ((e >> 6) == (e & 63)) ? 1.f : 0.f;
    }
    __syncthreads();
    for (int it = 0; it < 8; ++it) {
        float* Tin  = (it & 1) ? T2 : T;
        float* Tout = (it & 1) ? T  : T2;
        for (int e = tid; e < 4096; e += 256) {
            int r = e >> 6, cc = e & 63;
            float a0 = 0, a1 = 0, a2 = 0, a3 = 0;
            #pragma unroll 8
            for (int k = 0; k < 64; k += 4) {
                a0 = fmaf(As[r * 64 + k],     Tin[k * 64 + cc],       a0);
                a1 = fmaf(As[r * 64 + k + 1], Tin[(k + 1) * 64 + cc], a1);
                a2 = fmaf(As[r * 64 + k + 2], Tin[(k + 2) * 64 + cc], a2);
                a3 = fmaf(As[r * 64 + k + 3], Tin[(k + 3) * 64 + cc], a3);
            }
            Tout[e] = ((r == cc) ? 1.f : 0.f) - ((a0 + a1) + (a2 + a3));
        }
        __syncthreads();
    }
    // 8 iterations: final result lives in T
    for (int e = tid; e < 6400; e += 256) {
        int i = e / 100, c = e % 100;
        float a0 = 0, a1 = 0, a2 = 0, a3 = 0;
        #pragma unroll 8
        for (int k = 0; k < 64; k += 4) {
            a0 = fmaf(T[i * 64 + k],     RHS_g[k * 100 + c],       a0);
            a1 = fmaf(T[i * 64 + k + 1], RHS_g[(k + 1) * 100 + c], a1);
            a2 = fmaf(T[i * 64 + k + 2], RHS_g[(k + 2) * 100 + c], a2);
            a3 = fmaf(T[i * 64 + k + 3], RHS_g[(k + 3) * 100 + c], a3);
        }
        float w = ((a0 + a1) + (a2 + a3)) * (1.0f / NP1);
        Ws[e] = w; W_g[e] = w;
    }
    __syncthreads();
    for (int e = tid; e < 4096; e += 256) {
        int k = e >> 6, l = e & 63;
        float a0 = 0, a1 = 0;
        #pragma unroll 10
        for (int c = 0; c < 100; c += 2) {
            a0 = fmaf(Ws[k * 100 + c],     Ws[l * 100 + c],     a0);
            a1 = fmaf(Ws[k * 100 + c + 1], Ws[l * 100 + c + 1], a1);
        }
        G_g[e] = (k == l) ? 0.0f : (a0 + a1);
    }
}

// ------------- macro-generated DCC scan: NO runtime-indexed arrays -------------
#define DECL1(k) float s##k = ((m >> (k)) & 1ull) ? 1.0f : -1.0f;
#define DECL4(a,b,c2,d) DECL1(a) DECL1(b) DECL1(c2) DECL1(d)
#define DECL_ALL \
  DECL4(0,1,2,3)   DECL4(4,5,6,7)   DECL4(8,9,10,11)  DECL4(12,13,14,15) \
  DECL4(16,17,18,19) DECL4(20,21,22,23) DECL4(24,25,26,27) DECL4(28,29,30,31) \
  DECL4(32,33,34,35) DECL4(36,37,38,39) DECL4(40,41,42,43) DECL4(44,45,46,47) \
  DECL4(48,49,50,51) DECL4(52,53,54,55) DECL4(56,57,58,59) DECL4(60,61,62,63)

#define FMA4(k0,k1,k2,k3) \
  f0 = fmaf(Gi[k0], s##k0, f0); \
  f1 = fmaf(Gi[k1], s##k1, f1); \
  f2 = fmaf(Gi[k2], s##k2, f2); \
  f3 = fmaf(Gi[k3], s##k3, f3);
#define FMA64 \
  FMA4(0,1,2,3)   FMA4(4,5,6,7)   FMA4(8,9,10,11)  FMA4(12,13,14,15) \
  FMA4(16,17,18,19) FMA4(20,21,22,23) FMA4(24,25,26,27) FMA4(28,29,30,31) \
  FMA4(32,33,34,35) FMA4(36,37,38,39) FMA4(40,41,42,43) FMA4(44,45,46,47) \
  FMA4(48,49,50,51) FMA4(52,53,54,55) FMA4(56,57,58,59) FMA4(60,61,62,63)

#define STEP(i) { \
    float p = fmaf(ETA_MU, *upp, Wc[(i) * NCLASS]); upp += ustr; \
    const float* __restrict__ Gi = Gg + (i) * 64; \
    float f0 = 0.f, f1 = 0.f, f2 = 0.f, f3 = 0.f; \
    FMA64 \
    s##i = ((p - ((f0 + f1) + (f2 + f3))) > 0.0f) ? 1.0f : -1.0f; \
}
#define STEP4(a,b,c2,d) STEP(a) STEP(b) STEP(c2) STEP(d)
#define STEP_ALL \
  STEP4(0,1,2,3)   STEP4(4,5,6,7)   STEP4(8,9,10,11)  STEP4(12,13,14,15) \
  STEP4(16,17,18,19) STEP4(20,21,22,23) STEP4(24,25,26,27) STEP4(28,29,30,31) \
  STEP4(32,33,34,35) STEP4(36,37,38,39) STEP4(40,41,42,43) STEP4(44,45,46,47) \
  STEP4(48,49,50,51) STEP4(52,53,54,55) STEP4(56,57,58,59) STEP4(60,61,62,63)

#define OUT1(k) if (s##k > 0.0f) mo |= (1ull << (k));
#define OUT4(a,b,c2,d) OUT1(a) OUT1(b) OUT1(c2) OUT1(d)
#define OUT_ALL \
  OUT4(0,1,2,3)   OUT4(4,5,6,7)   OUT4(8,9,10,11)  OUT4(12,13,14,15) \
  OUT4(16,17,18,19) OUT4(20,21,22,23) OUT4(24,25,26,27) OUT4(28,29,30,31) \
  OUT4(32,33,34,35) OUT4(36,37,38,39) OUT4(40,41,42,43) OUT4(44,45,46,47) \
  OUT4(48,49,50,51) OUT4(52,53,54,55) OUT4(56,57,58,59) OUT4(60,61,62,63)

// one DCC pass: thread-per-column, signs in 64 NAMED registers (no array)
__global__ __launch_bounds__(256) void k_scan(unsigned long long* __restrict__ Bmask,
                                              const int* __restrict__ labelY,
                                              const int* __restrict__ ovr,
                                              const float* __restrict__ Wg,
                                              const float* __restrict__ Gg,
                                              const float* __restrict__ U,
                                              const float* __restrict__ u) {
    int j = blockIdx.x * 256 + threadIdx.x;
    if (j >= NTRAIN) return;
    unsigned long long m = Bmask[j];
    int c = labelY[j];
    int ov = ovr[j];
    const float* upp; int ustr;
    if (ov) { upp = u + (ov - 1) * NBIT; ustr = 1; }
    else    { upp = U + j;               ustr = NTRAIN; }
    const float* __restrict__ Wc = Wg + c;
    DECL_ALL
    STEP_ALL
    unsigned long long mo = 0ull;
    OUT_ALL
    Bmask[j] = mo;
}

// likelihood: thread-per-column; U column in regs, u rows via uniform scalar loads
__global__ __launch_bounds__(256) void k_lik(const float* __restrict__ U,
                                             const float* __restrict__ u,
                                             const int* __restrict__ labelY,
                                             const int* __restrict__ ovr,
                                             const int* __restrict__ ylab,
                                             float* __restrict__ partials) {
    __shared__ float sbuf[8];
    int j = blockIdx.x * 256 + threadIdx.x;
    float acc = 0.0f;
    if (j < NTRAIN) {
        int ov = ovr[j];
        const float* up; int ustr;
        if (ov) { up = u + (ov - 1) * NBIT; ustr = 1; }
        else    { up = U + j;               ustr = NTRAIN; }
        float Ucol[NBIT];
        #pragma unroll
        for (int i = 0; i < NBIT; ++i) Ucol[i] = up[i * ustr];
        int cj = labelY[j];
        for (int b = 0; b < NBATCH; ++b) {
            const float* ub = u + b * NBIT;
            float a0 = 0, a1 = 0, a2 = 0, a3 = 0;
            #pragma unroll
            for (int i = 0; i < NBIT; i += 4) {
                a0 = fmaf(ub[i],     Ucol[i],     a0);
                a1 = fmaf(ub[i + 1], Ucol[i + 1], a1);
                a2 = fmaf(ub[i + 2], Ucol[i + 2], a2);
                a3 = fmaf(ub[i + 3], Ucol[i + 3], a3);
            }
            float ip = 0.5f * ((a0 + a1) + (a2 + a3));
            float aip = fabsf(ip);
            float t = __logf(1.0f + __expf(-aip)) + fmaxf(ip, 0.0f);
            if (ylab[b] == cj) t -= ip;
            acc += t;
        }
    }
    float tot = blk_reduce_sum(acc, sbuf);
    if (threadIdx.x == 0) partials[blockIdx.x] = tot;
}

__global__ void k_clreg(const float* __restrict__ Wg,
                        const unsigned long long* __restrict__ Bmask,
                        const int* __restrict__ ind,
                        const float* __restrict__ y,
                        float* __restrict__ clreg) {
    __shared__ float sbuf[8];
    __shared__ unsigned long long mB[NBATCH];
    int tid = threadIdx.x;
    if (tid < NBATCH) mB[tid] = Bmask[ind[tid]];
    __syncthreads();
    float accCl = 0.f;
    for (int e = tid; e < NCLASS * NBATCH; e += 256) {
        int b = e & 127, c = e >> 7;
        unsigned long long m = mB[b];
        float d0 = 0.f;
        #pragma unroll
        for (int i = 0; i < NBIT; ++i) {
            float w = Wg[i * NCLASS + c];
            d0 += ((m >> i) & 1ull) ? w : -w;
        }
        float diff = y[b * NCLASS + c] - d0;
        accCl = fmaf(diff, diff, accCl);
    }
    float accRg = 0.f;
    for (int e = tid; e < NBIT * NCLASS; e += 256) {
        float w = Wg[e];
        accRg = fmaf(w, w, accRg);
    }
    float clS = blk_reduce_sum(accCl, sbuf);
    float rgS = blk_reduce_sum(accRg, sbuf);
    if (tid == 0) { clreg[0] = clS; clreg[1] = rgS; }
}

__global__ void k_final(const float* __restrict__ partials,
                        const float* __restrict__ clreg,
                        float* __restrict__ out) {
    __shared__ float sbuf[8];
    int tid = threadIdx.x;
    float a = 0.f;
    for (int i = tid; i < NBLK; i += 256) a += partials[i];
    float lik = blk_reduce_sum(a, sbuf);
    if (tid == 0) {
        out[0] = lik * (1.0f / ((float)NBATCH * (float)NTRAIN))
               + clreg[0] * (1.0f / (float)(NCLASS * NBATCH))
               + clreg[1] * (1.0f / (float)(NBIT * NCLASS));
    }
}

extern "C" void kernel_launch(void* const* d_in, const int* in_sizes, int n_in,
                              void* d_out, int out_size, void* d_ws, size_t ws_size,
                              hipStream_t stream) {
    const float* u   = (const float*)d_in[0];
    const float* y   = (const float*)d_in[1];
    const float* U   = (const float*)d_in[2];
    const float* B   = (const float*)d_in[3];
    const float* Y   = (const float*)d_in[4];
    const int*   ind = (const int*)d_in[5];

    char* ws = (char*)d_ws;
    unsigned long long* Bmask  = (unsigned long long*)(ws + OFF_BMASK);
    unsigned long long* planes = (unsigned long long*)(ws + OFF_PLANES);
    unsigned long long* cmask  = (unsigned long long*)(ws + OFF_CMASK);
    int*   labelY = (int*)(ws + OFF_LABELY);
    int*   ovr    = (int*)(ws + OFF_OVR);
    int*   ylab   = (int*)(ws + OFF_YLAB);
    int*   ccount = (int*)(ws + OFF_CCOUNT);
    float* A      = (float*)(ws + OFF_A);
    float* RHS    = (float*)(ws + OFF_RHS);
    float* W      = (float*)(ws + OFF_W);
    float* G      = (float*)(ws + OFF_G);
    float* part   = (float*)(ws + OFF_PART);
    float* clreg  = (float*)(ws + OFF_CLREG);

    hipMemsetAsync(ovr,   0, NTRAIN * sizeof(int), stream);
    hipMemsetAsync(cmask, 0, (size_t)NCLASS * NWP * sizeof(unsigned long long), stream);

    k_prep   <<<NBLK, 256, 0, stream>>>(Y, B, labelY, Bmask);
    k_scatter<<<1, 128, 0, stream>>>(y, ind, labelY, ovr, ylab);
    k_cmask  <<<NBLK, 256, 0, stream>>>(labelY, cmask);
    k_counts <<<1, 128, 0, stream>>>(cmask, ccount);

    for (int pass = 0; pass < 3; ++pass) {
        k_transpose<<<NBLK, 256, 0, stream>>>(Bmask, planes);
        k_bbt_byt  <<<64, 256, 0, stream>>>(planes, cmask, ccount, A, RHS);
        k_solve    <<<1, 256, 0, stream>>>(A, RHS, W, G);
        k_scan     <<<NBLK, 256, 0, stream>>>(Bmask, labelY, ovr, W, G, U, u);
    }

    k_lik  <<<NBLK, 256, 0, stream>>>(U, u, labelY, ovr, ylab, part);
    k_clreg<<<1, 256, 0, stream>>>(W, Bmask, ind, y, clreg);
    k_final<<<1, 256, 0, stream>>>(part, clreg, (float*)d_out);
}

// Round 3
// 718.387 us; speedup vs baseline: 2.5804x; 1.7829x over previous
//
#include <hip/hip_runtime.h>
#include <hip/hip_bf16.h>

#define NTRAIN 100000
#define NBIT   64
#define NCLASS 100
#define NBATCH 128
#define NW     1563   /* ceil(100000/64) */
#define NWP    1568   /* padded stride   */
#define NP1    100001.0f
#define ETA_MU 55.0f

#define NBLK   391    /* ceil(100000/256) */
#define CCH    32     /* words per k_bbt2 chunk */
#define NCHUNK 49     /* ceil(NW/CCH) -> 49*32 = 1568 */

typedef unsigned long long u64;

// ---------------- workspace layout (bytes) ----------------
#define OFF_BMASK   0u                       /* u64[100000]      800000 */
#define OFF_PLANES  800000u                  /* u64[64][1568]    802816 */
#define OFF_CMASK   1602816u                 /* u64[100][1568]  1254400 */
#define OFF_LABELY  2857216u                 /* int[100000]      400000 */
#define OFF_OVR     3257216u                 /* int[100000]      400000 */
#define OFF_YLAB    3657216u                 /* int[128]            512 */
#define OFF_CCOUNT  3657728u                 /* int[100]            512 */
#define OFF_W       3700224u                 /* f32[64][100]      25600 */
#define OFF_G       3725824u                 /* f32[64][64]       16384 */
#define OFF_PART    3742208u                 /* f32[391]                */
#define OFF_CLREG   3744256u                 /* f32[2]                  */
#define OFF_IA      3744512u                 /* int[4096]         16384 */
#define OFF_IB      3760896u                 /* int[6400]         25600 */
#define OFF_WT      3786496u                 /* f32[100][64]      25600 */

__device__ __forceinline__ float blk_reduce_sum(float v, float* sbuf) {
    int tid = threadIdx.x;
    for (int off = 32; off > 0; off >>= 1) v += __shfl_down(v, off, 64);
    __syncthreads();
    if ((tid & 63) == 0) sbuf[tid >> 6] = v;
    __syncthreads();
    float t = 0.f;
    if (tid == 0) {
        int nw = (int)(blockDim.x >> 6);
        for (int q = 0; q < nw; ++q) t += sbuf[q];
    }
    return t;   // valid on tid 0 only
}

// fused: label of every training column + B sign-mask per column
__global__ __launch_bounds__(256) void k_prep(const float* __restrict__ Y,
                                              const float* __restrict__ B,
                                              int* __restrict__ labelY,
                                              u64* __restrict__ Bmask) {
    int j = blockIdx.x * 256 + threadIdx.x;
    if (j >= NTRAIN) return;
    int lab = 0;
    for (int r = 0; r < NCLASS; ++r)
        if (Y[r * NTRAIN + j] > 0.5f) lab = r;
    labelY[j] = lab;
    u64 m = 0ull;
    #pragma unroll
    for (int i = 0; i < NBIT; ++i)
        if (B[i * NTRAIN + j] > 0.0f) m |= (1ull << i);
    Bmask[j] = m;
}

// batch labels + sequential (last-wins) scatter of labelY / override table
__global__ void k_scatter(const float* __restrict__ y, const int* __restrict__ ind,
                          int* __restrict__ labelY, int* __restrict__ ovr,
                          int* __restrict__ ylab) {
    __shared__ int cls[NBATCH], idx[NBATCH];
    int k = threadIdx.x;
    if (k < NBATCH) {
        int c = 0;
        for (int r = 0; r < NCLASS; ++r)
            if (y[k * NCLASS + r] > 0.5f) c = r;
        cls[k] = c; idx[k] = ind[k]; ylab[k] = c;
    }
    __syncthreads();
    if (k == 0) {
        for (int q = 0; q < NBATCH; ++q) {
            labelY[idx[q]] = cls[q];
            ovr[idx[q]] = q + 1;
        }
    }
}

// per-class column bitmasks (atomicOr is order-independent -> deterministic)
__global__ __launch_bounds__(256) void k_cmask(const int* __restrict__ labelY,
                                               u64* __restrict__ cmask) {
    int j = blockIdx.x * 256 + threadIdx.x;
    if (j >= NTRAIN) return;
    int c = labelY[j];
    atomicOr(&cmask[(size_t)c * NWP + (j >> 6)], 1ull << (j & 63));
}

// class sizes: one block per class, coalesced word-strided popcount
__global__ __launch_bounds__(256) void k_counts(const u64* __restrict__ cmask,
                                                int* __restrict__ ccount) {
    __shared__ int sb[4];
    int c = blockIdx.x, tid = threadIdx.x;
    int cnt = 0;
    for (int w = tid; w < NW; w += 256) cnt += __popcll(cmask[(size_t)c * NWP + w]);
    for (int off = 32; off > 0; off >>= 1) cnt += __shfl_down(cnt, off, 64);
    if ((tid & 63) == 0) sb[tid >> 6] = cnt;
    __syncthreads();
    if (tid == 0) ccount[c] = sb[0] + sb[1] + sb[2] + sb[3];
}

// column-masks -> row bitplanes (64x64 bit transpose via ballot)
__global__ __launch_bounds__(256) void k_transpose(const u64* __restrict__ Bmask,
                                                   u64* __restrict__ planes) {
    int gid = blockIdx.x * 256 + threadIdx.x;
    int w = gid >> 6, lane = threadIdx.x & 63;
    if (w >= NW) return;
    int j = w * 64 + lane;
    u64 m = (j < NTRAIN) ? Bmask[j] : 0ull;
    u64 acc = 0ull;
    #pragma unroll
    for (int i = 0; i < 64; ++i) {
        u64 bal = __ballot((m >> i) & 1ull);
        if (lane == i) acc = bal;
    }
    planes[(size_t)lane * NWP + w] = acc;
}

// chunked BB^T / BY^T: LDS-staged coalesced reads, int atomic partials.
// iA[k][l] += popcll(pk^pl) over this block's 32 words;
// iB[k][c] += popcll(pk&cm_c).
__global__ __launch_bounds__(256) void k_bbt2(const u64* __restrict__ planes,
                                              const u64* __restrict__ cmask,
                                              int* __restrict__ iA,
                                              int* __restrict__ iB) {
    __shared__ u64 Lp[64 * 33];    /* +1 word pad per row: 2-way-free banks */
    __shared__ u64 Lc[100 * 33];
    int tid = threadIdx.x;
    int w0 = blockIdx.x * CCH;
    for (int idx = tid; idx < 64 * CCH; idx += 256) {
        int r = idx >> 5, w = idx & 31;
        int gw = w0 + w;
        Lp[r * 33 + w] = (gw < NW) ? planes[(size_t)r * NWP + gw] : 0ull;
    }
    for (int idx = tid; idx < 100 * CCH; idx += 256) {
        int r = idx >> 5, w = idx & 31;
        int gw = w0 + w;
        Lc[r * 33 + w] = (gw < NW) ? cmask[(size_t)r * NWP + gw] : 0ull;
    }
    __syncthreads();
    int k = tid & 63, grp = tid >> 6;
    int cntA[16], cntB[25];
    #pragma unroll
    for (int i = 0; i < 16; ++i) cntA[i] = 0;
    #pragma unroll
    for (int i = 0; i < 25; ++i) cntB[i] = 0;
    for (int w = 0; w < CCH; ++w) {
        u64 pkw = Lp[k * 33 + w];
        #pragma unroll
        for (int li = 0; li < 16; ++li)
            cntA[li] += __popcll(pkw ^ Lp[(grp + 4 * li) * 33 + w]);
        #pragma unroll
        for (int ci = 0; ci < 25; ++ci)
            cntB[ci] += __popcll(pkw & Lc[(grp * 25 + ci) * 33 + w]);
    }
    #pragma unroll
    for (int li = 0; li < 16; ++li)
        atomicAdd(&iA[k * 64 + grp + 4 * li], cntA[li]);
    #pragma unroll
    for (int ci = 0; ci < 25; ++ci)
        atomicAdd(&iB[k * 100 + grp * 25 + ci], cntB[ci]);
}

// finalize ints -> A, Neumann inverse (6 iters, ||A||~0.05), W, W^T, G.
// G has a ZERO diagonal (k_scan's update excludes the i-th term).
// Also zeroes iA/iB for the next pass's atomics.
__global__ __launch_bounds__(1024) void k_solve(const int* __restrict__ iA_g,
                                                const int* __restrict__ iB_g,
                                                const int* __restrict__ ccount,
                                                int* __restrict__ iA_z,
                                                int* __restrict__ iB_z,
                                                float* __restrict__ W_g,
                                                float* __restrict__ WT_g,
                                                float* __restrict__ G_g) {
    __shared__ float T[4096], T2[4096];
    __shared__ float Ws[6400];          /* phase A: holds As; phase B: holds W^T */
    int tid = threadIdx.x;
    for (int e = tid; e < 4096; e += 1024) {
        int r = e >> 6, cc = e & 63;
        int v = iA_g[e];
        Ws[e] = (r == cc) ? 0.0f : (float)(NTRAIN - 2 * v) * (1.0f / NP1);
        T[e] = (r == cc) ? 1.f : 0.f;
    }
    __syncthreads();
    for (int it = 0; it < 6; ++it) {        /* even count -> result in T */
        float* Tin  = (it & 1) ? T  : T2;
        float* Tout = (it & 1) ? T2 : T;
        // NOTE swapped naming: it0 reads T writes T2 ... define explicitly:
        Tin  = (it & 1) ? T2 : T;
        Tout = (it & 1) ? T  : T2;
        for (int e = tid; e < 4096; e += 1024) {
            int r = e >> 6, cc = e & 63;
            const float* As = Ws + r * 64;
            float a0 = 0, a1 = 0, a2 = 0, a3 = 0;
            #pragma unroll 8
            for (int k = 0; k < 64; k += 4) {
                a0 = fmaf(As[k],     Tin[k * 64 + cc],       a0);
                a1 = fmaf(As[k + 1], Tin[(k + 1) * 64 + cc], a1);
                a2 = fmaf(As[k + 2], Tin[(k + 2) * 64 + cc], a2);
                a3 = fmaf(As[k + 3], Tin[(k + 3) * 64 + cc], a3);
            }
            Tout[e] = ((r == cc) ? 1.f : 0.f) - ((a0 + a1) + (a2 + a3));
        }
        __syncthreads();
    }
    /* it=5 wrote T2?  iters: it0: in=T out=T2; it1: in=T2 out=T; ...
       it5: in=T2 out=T  -> final inverse-scaled lives in T. */
    // W = T @ RHS / NP1, RHS[k][c] = 2*iB - ccount[c]; store W^T into Ws (LDS)
    for (int e = tid; e < 6400; e += 1024) {
        int i = e / 100, c = e % 100;
        float a0 = 0, a1 = 0, a2 = 0, a3 = 0;
        #pragma unroll 8
        for (int k = 0; k < 64; k += 4) {
            float r0 = (float)(2 * iB_g[k * 100 + c]       - ccount[c]);
            float r1 = (float)(2 * iB_g[(k + 1) * 100 + c] - ccount[c]);
            float r2 = (float)(2 * iB_g[(k + 2) * 100 + c] - ccount[c]);
            float r3 = (float)(2 * iB_g[(k + 3) * 100 + c] - ccount[c]);
            a0 = fmaf(T[i * 64 + k],     r0, a0);
            a1 = fmaf(T[i * 64 + k + 1], r1, a1);
            a2 = fmaf(T[i * 64 + k + 2], r2, a2);
            a3 = fmaf(T[i * 64 + k + 3], r3, a3);
        }
        float w = ((a0 + a1) + (a2 + a3)) * (1.0f / NP1);
        W_g[e] = w;
        WT_g[c * 64 + i] = w;
        Ws[c * 64 + i] = w;     /* W^T layout in LDS for the gram below */
    }
    __syncthreads();
    // G = W W^T (zero diag) from LDS W^T: G[k][l] = sum_c WT[c][k]*WT[c][l]
    for (int e = tid; e < 4096; e += 1024) {
        int k = e >> 6, l = e & 63;
        float a0 = 0, a1 = 0;
        #pragma unroll 10
        for (int c = 0; c < 100; c += 2) {
            a0 = fmaf(Ws[c * 64 + k],       Ws[c * 64 + l],       a0);
            a1 = fmaf(Ws[(c + 1) * 64 + k], Ws[(c + 1) * 64 + l], a1);
        }
        G_g[e] = (k == l) ? 0.0f : (a0 + a1);
    }
    // zero accumulators for next pass
    for (int e = tid; e < 4096; e += 1024) iA_z[e] = 0;
    for (int e = tid; e < 6400; e += 1024) iB_z[e] = 0;
}

// ------------- macro-generated DCC scan: NO runtime-indexed arrays -------------
#define DECL1(k) float s##k = ((m >> (k)) & 1ull) ? 1.0f : -1.0f;
#define DECL4(a,b,c2,d) DECL1(a) DECL1(b) DECL1(c2) DECL1(d)
#define DECL_ALL \
  DECL4(0,1,2,3)   DECL4(4,5,6,7)   DECL4(8,9,10,11)  DECL4(12,13,14,15) \
  DECL4(16,17,18,19) DECL4(20,21,22,23) DECL4(24,25,26,27) DECL4(28,29,30,31) \
  DECL4(32,33,34,35) DECL4(36,37,38,39) DECL4(40,41,42,43) DECL4(44,45,46,47) \
  DECL4(48,49,50,51) DECL4(52,53,54,55) DECL4(56,57,58,59) DECL4(60,61,62,63)

#define FMA4(k0,k1,k2,k3) \
  f0 = fmaf(Gi[k0], s##k0, f0); \
  f1 = fmaf(Gi[k1], s##k1, f1); \
  f2 = fmaf(Gi[k2], s##k2, f2); \
  f3 = fmaf(Gi[k3], s##k3, f3);
#define FMA64 \
  FMA4(0,1,2,3)   FMA4(4,5,6,7)   FMA4(8,9,10,11)  FMA4(12,13,14,15) \
  FMA4(16,17,18,19) FMA4(20,21,22,23) FMA4(24,25,26,27) FMA4(28,29,30,31) \
  FMA4(32,33,34,35) FMA4(36,37,38,39) FMA4(40,41,42,43) FMA4(44,45,46,47) \
  FMA4(48,49,50,51) FMA4(52,53,54,55) FMA4(56,57,58,59) FMA4(60,61,62,63)

#define STEP(i) { \
    float p = fmaf(ETA_MU, *upp, WTc[(i)]); upp += ustr; \
    const float* __restrict__ Gi = Gg + (i) * 64; \
    float f0 = 0.f, f1 = 0.f, f2 = 0.f, f3 = 0.f; \
    FMA64 \
    s##i = ((p - ((f0 + f1) + (f2 + f3))) > 0.0f) ? 1.0f : -1.0f; \
}
#define STEP4(a,b,c2,d) STEP(a) STEP(b) STEP(c2) STEP(d)
#define STEP_ALL \
  STEP4(0,1,2,3)   STEP4(4,5,6,7)   STEP4(8,9,10,11)  STEP4(12,13,14,15) \
  STEP4(16,17,18,19) STEP4(20,21,22,23) STEP4(24,25,26,27) STEP4(28,29,30,31) \
  STEP4(32,33,34,35) STEP4(36,37,38,39) STEP4(40,41,42,43) STEP4(44,45,46,47) \
  STEP4(48,49,50,51) STEP4(52,53,54,55) STEP4(56,57,58,59) STEP4(60,61,62,63)

#define OUT1(k) if (s##k > 0.0f) mo |= (1ull << (k));
#define OUT4(a,b,c2,d) OUT1(a) OUT1(b) OUT1(c2) OUT1(d)
#define OUT_ALL \
  OUT4(0,1,2,3)   OUT4(4,5,6,7)   OUT4(8,9,10,11)  OUT4(12,13,14,15) \
  OUT4(16,17,18,19) OUT4(20,21,22,23) OUT4(24,25,26,27) OUT4(28,29,30,31) \
  OUT4(32,33,34,35) OUT4(36,37,38,39) OUT4(40,41,42,43) OUT4(44,45,46,47) \
  OUT4(48,49,50,51) OUT4(52,53,54,55) OUT4(56,57,58,59) OUT4(60,61,62,63)

// one DCC pass: thread-per-column, signs in 64 NAMED registers, W^T staged in LDS
__global__ __launch_bounds__(256) void k_scan(u64* __restrict__ Bmask,
                                              const int* __restrict__ labelY,
                                              const int* __restrict__ ovr,
                                              const float* __restrict__ WT,
                                              const float* __restrict__ Gg,
                                              const float* __restrict__ U,
                                              const float* __restrict__ u) {
    __shared__ float WTs[6400];
    int tid = threadIdx.x;
    for (int idx = tid; idx < 6400; idx += 256) WTs[idx] = WT[idx];
    __syncthreads();
    int j = blockIdx.x * 256 + tid;
    if (j >= NTRAIN) return;
    u64 m = Bmask[j];
    int c = labelY[j];
    int ov = ovr[j];
    const float* upp; int ustr;
    if (ov) { upp = u + (ov - 1) * NBIT; ustr = 1; }
    else    { upp = U + j;               ustr = NTRAIN; }
    const float* WTc = WTs + c * 64;
    DECL_ALL
    STEP_ALL
    unsigned long long mo = 0ull;
    OUT_ALL
    Bmask[j] = mo;
}

// likelihood: thread-per-column; U column in regs, u rows via uniform scalar loads
__global__ __launch_bounds__(256) void k_lik(const float* __restrict__ U,
                                             const float* __restrict__ u,
                                             const int* __restrict__ labelY,
                                             const int* __restrict__ ovr,
                                             const int* __restrict__ ylab,
                                             float* __restrict__ partials) {
    __shared__ float sbuf[8];
    int j = blockIdx.x * 256 + threadIdx.x;
    float acc = 0.0f;
    if (j < NTRAIN) {
        int ov = ovr[j];
        const float* up; int ustr;
        if (ov) { up = u + (ov - 1) * NBIT; ustr = 1; }
        else    { up = U + j;               ustr = NTRAIN; }
        float Ucol[NBIT];
        #pragma unroll
        for (int i = 0; i < NBIT; ++i) Ucol[i] = up[i * ustr];
        int cj = labelY[j];
        for (int b = 0; b < NBATCH; ++b) {
            const float* ub = u + b * NBIT;
            float a0 = 0, a1 = 0, a2 = 0, a3 = 0;
            #pragma unroll
            for (int i = 0; i < NBIT; i += 4) {
                a0 = fmaf(ub[i],     Ucol[i],     a0);
                a1 = fmaf(ub[i + 1], Ucol[i + 1], a1);
                a2 = fmaf(ub[i + 2], Ucol[i + 2], a2);
                a3 = fmaf(ub[i + 3], Ucol[i + 3], a3);
            }
            float ip = 0.5f * ((a0 + a1) + (a2 + a3));
            float aip = fabsf(ip);
            float t = __logf(1.0f + __expf(-aip)) + fmaxf(ip, 0.0f);
            if (ylab[b] == cj) t -= ip;
            acc += t;
        }
    }
    float tot = blk_reduce_sum(acc, sbuf);
    if (threadIdx.x == 0) partials[blockIdx.x] = tot;
}

__global__ void k_clreg(const float* __restrict__ Wg,
                        const u64* __restrict__ Bmask,
                        const int* __restrict__ ind,
                        const float* __restrict__ y,
                        float* __restrict__ clreg) {
    __shared__ float sbuf[8];
    __shared__ u64 mB[NBATCH];
    int tid = threadIdx.x;
    if (tid < NBATCH) mB[tid] = Bmask[ind[tid]];
    __syncthreads();
    float accCl = 0.f;
    for (int e = tid; e < NCLASS * NBATCH; e += 256) {
        int b = e & 127, c = e >> 7;
        u64 m = mB[b];
        float d0 = 0.f;
        #pragma unroll
        for (int i = 0; i < NBIT; ++i) {
            float w = Wg[i * NCLASS + c];
            d0 += ((m >> i) & 1ull) ? w : -w;
        }
        float diff = y[b * NCLASS + c] - d0;
        accCl = fmaf(diff, diff, accCl);
    }
    float accRg = 0.f;
    for (int e = tid; e < NBIT * NCLASS; e += 256) {
        float w = Wg[e];
        accRg = fmaf(w, w, accRg);
    }
    float clS = blk_reduce_sum(accCl, sbuf);
    float rgS = blk_reduce_sum(accRg, sbuf);
    if (tid == 0) { clreg[0] = clS; clreg[1] = rgS; }
}

__global__ void k_final(const float* __restrict__ partials,
                        const float* __restrict__ clreg,
                        float* __restrict__ out) {
    __shared__ float sbuf[8];
    int tid = threadIdx.x;
    float a = 0.f;
    for (int i = tid; i < NBLK; i += 256) a += partials[i];
    float lik = blk_reduce_sum(a, sbuf);
    if (tid == 0) {
        out[0] = lik * (1.0f / ((float)NBATCH * (float)NTRAIN))
               + clreg[0] * (1.0f / (float)(NCLASS * NBATCH))
               + clreg[1] * (1.0f / (float)(NBIT * NCLASS));
    }
}

extern "C" void kernel_launch(void* const* d_in, const int* in_sizes, int n_in,
                              void* d_out, int out_size, void* d_ws, size_t ws_size,
                              hipStream_t stream) {
    const float* u   = (const float*)d_in[0];
    const float* y   = (const float*)d_in[1];
    const float* U   = (const float*)d_in[2];
    const float* B   = (const float*)d_in[3];
    const float* Y   = (const float*)d_in[4];
    const int*   ind = (const int*)d_in[5];

    char* ws = (char*)d_ws;
    u64*   Bmask  = (u64*)(ws + OFF_BMASK);
    u64*   planes = (u64*)(ws + OFF_PLANES);
    u64*   cmask  = (u64*)(ws + OFF_CMASK);
    int*   labelY = (int*)(ws + OFF_LABELY);
    int*   ovr    = (int*)(ws + OFF_OVR);
    int*   ylab   = (int*)(ws + OFF_YLAB);
    int*   ccount = (int*)(ws + OFF_CCOUNT);
    float* W      = (float*)(ws + OFF_W);
    float* G      = (float*)(ws + OFF_G);
    float* part   = (float*)(ws + OFF_PART);
    float* clreg  = (float*)(ws + OFF_CLREG);
    int*   iA     = (int*)(ws + OFF_IA);
    int*   iB     = (int*)(ws + OFF_IB);
    float* WT     = (float*)(ws + OFF_WT);

    hipMemsetAsync(ovr,   0, NTRAIN * sizeof(int), stream);
    hipMemsetAsync(cmask, 0, (size_t)NCLASS * NWP * sizeof(u64), stream);
    hipMemsetAsync(iA,    0, (4096 + 6400) * sizeof(int), stream);  /* iA+iB contiguous */

    k_prep   <<<NBLK, 256, 0, stream>>>(Y, B, labelY, Bmask);
    k_scatter<<<1, 128, 0, stream>>>(y, ind, labelY, ovr, ylab);
    k_cmask  <<<NBLK, 256, 0, stream>>>(labelY, cmask);
    k_counts <<<NCLASS, 256, 0, stream>>>(cmask, ccount);

    for (int pass = 0; pass < 3; ++pass) {
        k_transpose<<<NBLK, 256, 0, stream>>>(Bmask, planes);
        k_bbt2     <<<NCHUNK, 256, 0, stream>>>(planes, cmask, iA, iB);
        k_solve    <<<1, 1024, 0, stream>>>(iA, iB, ccount, iA, iB, W, WT, G);
        k_scan     <<<NBLK, 256, 0, stream>>>(Bmask, labelY, ovr, WT, G, U, u);
    }

    k_lik  <<<NBLK, 256, 0, stream>>>(U, u, labelY, ovr, ylab, part);
    k_clreg<<<1, 256, 0, stream>>>(W, Bmask, ind, y, clreg);
    k_final<<<1, 256, 0, stream>>>(part, clreg, (float*)d_out);
}

// Round 4
// 637.193 us; speedup vs baseline: 2.9092x; 1.1274x over previous
//
#include <hip/hip_runtime.h>
#include <hip/hip_bf16.h>

#define NTRAIN 100000
#define NBIT   64
#define NCLASS 100
#define NBATCH 128
#define NW     1563   /* ceil(100000/64) */
#define NWP    1568   /* padded stride   */
#define NP1    100001.0f
#define ETA_MU 55.0f

#define NBLK   391    /* ceil(100000/256) */
#define NBLK4  1563   /* ceil(100000*4/256): 4 lanes per column */
#define CCH    32     /* words per k_bbt2 chunk */
#define NCHUNK 49     /* ceil(NW/CCH) -> 49*32 = 1568 */
#define GSTR   68     /* padded LDS stride for G rows */

typedef unsigned long long u64;
typedef unsigned int u32;

// ---------------- workspace layout (bytes) ----------------
#define OFF_BMASK   0u                       /* u64[100000]      800000 */
#define OFF_PLANES  800000u                  /* u64[64][1568]    802816 */
#define OFF_CMASK   1602816u                 /* u64[100][1568]  1254400 */
#define OFF_LABELY  2857216u                 /* int[100000]      400000 */
#define OFF_OVR     3257216u                 /* int[100000]      400000 */
#define OFF_YLAB    3657216u                 /* int[128]            512 */
#define OFF_CCOUNT  3657728u                 /* int[100]            512 */
#define OFF_W       3700224u                 /* f32[64][100]      25600 */
#define OFF_G       3725824u                 /* f32[64][64]       16384 */
#define OFF_PART    3742208u                 /* f32[391]                */
#define OFF_CLREG   3744256u                 /* f32[2]                  */
#define OFF_IA      3744512u                 /* int[4096]         16384 */
#define OFF_IB      3760896u                 /* int[6400]         25600 */
#define OFF_WT      3786496u                 /* f32[100][64]      25600 */

__device__ __forceinline__ float blk_reduce_sum(float v, float* sbuf) {
    int tid = threadIdx.x;
    for (int off = 32; off > 0; off >>= 1) v += __shfl_down(v, off, 64);
    __syncthreads();
    if ((tid & 63) == 0) sbuf[tid >> 6] = v;
    __syncthreads();
    float t = 0.f;
    if (tid == 0) {
        int nw = (int)(blockDim.x >> 6);
        for (int q = 0; q < nw; ++q) t += sbuf[q];
    }
    return t;   // valid on tid 0 only
}

// batch labels + sequential (last-wins) override table (runs FIRST)
__global__ void k_scatter(const float* __restrict__ y, const int* __restrict__ ind,
                          int* __restrict__ ovr, int* __restrict__ ylab) {
    __shared__ int cls[NBATCH], idx[NBATCH];
    int k = threadIdx.x;
    if (k < NBATCH) {
        int c = 0;
        for (int r = 0; r < NCLASS; ++r)
            if (y[k * NCLASS + r] > 0.5f) c = r;
        cls[k] = c; idx[k] = ind[k]; ylab[k] = c;
    }
    __syncthreads();
    if (k == 0) {
        for (int q = 0; q < NBATCH; ++q) ovr[idx[q]] = q + 1;
    }
}

// fused: final label per column (Y or override), B sign-mask, class bitmask
__global__ __launch_bounds__(256) void k_prep(const float* __restrict__ Y,
                                              const float* __restrict__ B,
                                              const int* __restrict__ ovr,
                                              const int* __restrict__ ylab,
                                              int* __restrict__ labelY,
                                              u64* __restrict__ Bmask,
                                              u64* __restrict__ cmask) {
    int j = blockIdx.x * 256 + threadIdx.x;
    if (j >= NTRAIN) return;
    int lab = 0;
    for (int r = 0; r < NCLASS; ++r)
        if (Y[r * NTRAIN + j] > 0.5f) lab = r;
    int ov = ovr[j];
    if (ov) lab = ylab[ov - 1];
    labelY[j] = lab;
    u64 m = 0ull;
    #pragma unroll
    for (int i = 0; i < NBIT; ++i)
        if (B[i * NTRAIN + j] > 0.0f) m |= (1ull << i);
    Bmask[j] = m;
    atomicOr(&cmask[(size_t)lab * NWP + (j >> 6)], 1ull << (j & 63));
}

// class sizes: one block per class, coalesced word-strided popcount
__global__ __launch_bounds__(256) void k_counts(const u64* __restrict__ cmask,
                                                int* __restrict__ ccount) {
    __shared__ int sb[4];
    int c = blockIdx.x, tid = threadIdx.x;
    int cnt = 0;
    for (int w = tid; w < NW; w += 256) cnt += __popcll(cmask[(size_t)c * NWP + w]);
    for (int off = 32; off > 0; off >>= 1) cnt += __shfl_down(cnt, off, 64);
    if ((tid & 63) == 0) sb[tid >> 6] = cnt;
    __syncthreads();
    if (tid == 0) ccount[c] = sb[0] + sb[1] + sb[2] + sb[3];
}

// column-masks -> row bitplanes (64x64 bit transpose via ballot)
__global__ __launch_bounds__(256) void k_transpose(const u64* __restrict__ Bmask,
                                                   u64* __restrict__ planes) {
    int gid = blockIdx.x * 256 + threadIdx.x;
    int w = gid >> 6, lane = threadIdx.x & 63;
    if (w >= NW) return;
    int j = w * 64 + lane;
    u64 m = (j < NTRAIN) ? Bmask[j] : 0ull;
    u64 acc = 0ull;
    #pragma unroll
    for (int i = 0; i < 64; ++i) {
        u64 bal = __ballot((m >> i) & 1ull);
        if (lane == i) acc = bal;
    }
    planes[(size_t)lane * NWP + w] = acc;
}

// chunked BB^T / BY^T: LDS-staged coalesced reads, int atomic partials
__global__ __launch_bounds__(256) void k_bbt2(const u64* __restrict__ planes,
                                              const u64* __restrict__ cmask,
                                              int* __restrict__ iA,
                                              int* __restrict__ iB) {
    __shared__ u64 Lp[64 * 33];
    __shared__ u64 Lc[100 * 33];
    int tid = threadIdx.x;
    int w0 = blockIdx.x * CCH;
    for (int idx = tid; idx < 64 * CCH; idx += 256) {
        int r = idx >> 5, w = idx & 31;
        int gw = w0 + w;
        Lp[r * 33 + w] = (gw < NW) ? planes[(size_t)r * NWP + gw] : 0ull;
    }
    for (int idx = tid; idx < 100 * CCH; idx += 256) {
        int r = idx >> 5, w = idx & 31;
        int gw = w0 + w;
        Lc[r * 33 + w] = (gw < NW) ? cmask[(size_t)r * NWP + gw] : 0ull;
    }
    __syncthreads();
    int k = tid & 63, grp = tid >> 6;
    int cntA[16], cntB[25];
    #pragma unroll
    for (int i = 0; i < 16; ++i) cntA[i] = 0;
    #pragma unroll
    for (int i = 0; i < 25; ++i) cntB[i] = 0;
    for (int w = 0; w < CCH; ++w) {
        u64 pkw = Lp[k * 33 + w];
        #pragma unroll
        for (int li = 0; li < 16; ++li)
            cntA[li] += __popcll(pkw ^ Lp[(grp + 4 * li) * 33 + w]);
        #pragma unroll
        for (int ci = 0; ci < 25; ++ci)
            cntB[ci] += __popcll(pkw & Lc[(grp * 25 + ci) * 33 + w]);
    }
    #pragma unroll
    for (int li = 0; li < 16; ++li)
        atomicAdd(&iA[k * 64 + grp + 4 * li], cntA[li]);
    #pragma unroll
    for (int ci = 0; ci < 25; ++ci)
        atomicAdd(&iB[k * 100 + grp * 25 + ci], cntB[ci]);
}

// finalize ints -> A, Neumann inverse (6 iters, ||A||~0.05), W, W^T, G (zero diag).
// Also zeroes iA/iB for the next pass's atomics.
__global__ __launch_bounds__(1024) void k_solve(const int* __restrict__ iA_g,
                                                const int* __restrict__ iB_g,
                                                const int* __restrict__ ccount,
                                                int* __restrict__ iA_z,
                                                int* __restrict__ iB_z,
                                                float* __restrict__ W_g,
                                                float* __restrict__ WT_g,
                                                float* __restrict__ G_g) {
    __shared__ float T[4096], T2[4096];
    __shared__ float Ws[6400];          /* phase A: holds As; phase B: holds W^T */
    int tid = threadIdx.x;
    for (int e = tid; e < 4096; e += 1024) {
        int r = e >> 6, cc = e & 63;
        int v = iA_g[e];
        Ws[e] = (r == cc) ? 0.0f : (float)(NTRAIN - 2 * v) * (1.0f / NP1);
        T[e] = (r == cc) ? 1.f : 0.f;
    }
    __syncthreads();
    for (int it = 0; it < 6; ++it) {        /* even count -> result in T */
        float* Tin  = (it & 1) ? T2 : T;
        float* Tout = (it & 1) ? T  : T2;
        for (int e = tid; e < 4096; e += 1024) {
            int r = e >> 6, cc = e & 63;
            const float* As = Ws + r * 64;
            float a0 = 0, a1 = 0, a2 = 0, a3 = 0;
            #pragma unroll 8
            for (int k = 0; k < 64; k += 4) {
                a0 = fmaf(As[k],     Tin[k * 64 + cc],       a0);
                a1 = fmaf(As[k + 1], Tin[(k + 1) * 64 + cc], a1);
                a2 = fmaf(As[k + 2], Tin[(k + 2) * 64 + cc], a2);
                a3 = fmaf(As[k + 3], Tin[(k + 3) * 64 + cc], a3);
            }
            Tout[e] = ((r == cc) ? 1.f : 0.f) - ((a0 + a1) + (a2 + a3));
        }
        __syncthreads();
    }
    for (int e = tid; e < 6400; e += 1024) {
        int i = e / 100, c = e % 100;
        float a0 = 0, a1 = 0, a2 = 0, a3 = 0;
        #pragma unroll 8
        for (int k = 0; k < 64; k += 4) {
            float r0 = (float)(2 * iB_g[k * 100 + c]       - ccount[c]);
            float r1 = (float)(2 * iB_g[(k + 1) * 100 + c] - ccount[c]);
            float r2 = (float)(2 * iB_g[(k + 2) * 100 + c] - ccount[c]);
            float r3 = (float)(2 * iB_g[(k + 3) * 100 + c] - ccount[c]);
            a0 = fmaf(T[i * 64 + k],     r0, a0);
            a1 = fmaf(T[i * 64 + k + 1], r1, a1);
            a2 = fmaf(T[i * 64 + k + 2], r2, a2);
            a3 = fmaf(T[i * 64 + k + 3], r3, a3);
        }
        float w = ((a0 + a1) + (a2 + a3)) * (1.0f / NP1);
        W_g[e] = w;
        WT_g[c * 64 + i] = w;
        Ws[c * 64 + i] = w;     /* W^T layout in LDS for the gram below */
    }
    __syncthreads();
    for (int e = tid; e < 4096; e += 1024) {
        int k = e >> 6, l = e & 63;
        float a0 = 0, a1 = 0;
        #pragma unroll 10
        for (int c = 0; c < 100; c += 2) {
            a0 = fmaf(Ws[c * 64 + k],       Ws[c * 64 + l],       a0);
            a1 = fmaf(Ws[(c + 1) * 64 + k], Ws[(c + 1) * 64 + l], a1);
        }
        G_g[e] = (k == l) ? 0.0f : (a0 + a1);
    }
    for (int e = tid; e < 4096; e += 1024) iA_z[e] = 0;
    for (int e = tid; e < 6400; e += 1024) iB_z[e] = 0;
}

// ---------------- quad-split DCC scan ----------------
// 4 lanes per column; lane q owns k = q*16 .. q*16+15 (signs s0..s15, p0..p15
// preloaded). Step i: 16 FMA vs LDS-staged G row + quad butterfly; owner lane
// commits the new sign. No memory on the chain except LDS G.

#define PRELD(t) \
    uv = ov ? ub[t] : uU[(t) * NTRAIN]; \
    float p##t = fmaf(ETA_MU, uv, wq[t]); \
    float s##t = ((mq >> (t)) & 1u) ? 1.0f : -1.0f;

#define LSTEP(i, X, Q) { \
    const float4* Gr = (const float4*)(Gs + (i) * GSTR + (q << 4)); \
    float4 ga = Gr[0], gb = Gr[1], gc = Gr[2], gd = Gr[3]; \
    float f0 = ga.x * s0, f1 = ga.y * s1, f2 = ga.z * s2, f3 = ga.w * s3; \
    f0 = fmaf(gb.x, s4,  f0); f1 = fmaf(gb.y, s5,  f1); \
    f2 = fmaf(gb.z, s6,  f2); f3 = fmaf(gb.w, s7,  f3); \
    f0 = fmaf(gc.x, s8,  f0); f1 = fmaf(gc.y, s9,  f1); \
    f2 = fmaf(gc.z, s10, f2); f3 = fmaf(gc.w, s11, f3); \
    f0 = fmaf(gd.x, s12, f0); f1 = fmaf(gd.y, s13, f1); \
    f2 = fmaf(gd.z, s14, f2); f3 = fmaf(gd.w, s15, f3); \
    float f = (f0 + f1) + (f2 + f3); \
    f += __shfl_xor(f, 1, 64); \
    f += __shfl_xor(f, 2, 64); \
    float nv = ((p##X - f) > 0.0f) ? 1.0f : -1.0f; \
    s##X = own##Q ? nv : s##X; \
}

#define OUTB(t) ch |= (s##t > 0.0f) ? (1u << (t)) : 0u;

__global__ __launch_bounds__(256) void k_scan4(u64* __restrict__ Bmask,
                                               const int* __restrict__ labelY,
                                               const int* __restrict__ ovr,
                                               const float* __restrict__ WT,
                                               const float* __restrict__ Gg,
                                               const float* __restrict__ U,
                                               const float* __restrict__ u) {
    __shared__ float Gs[64 * GSTR];
    int tid = threadIdx.x;
    for (int e = tid; e < 4096; e += 256)
        Gs[(e >> 6) * GSTR + (e & 63)] = Gg[e];
    __syncthreads();
    int j = blockIdx.x * 64 + (tid >> 2);
    if (j >= NTRAIN) return;
    int q = tid & 3;
    u64 m = Bmask[j];
    int c = labelY[j];
    int ov = ovr[j];
    u32 mq = (u32)(m >> (q << 4));
    const float* __restrict__ wq = WT + c * 64 + (q << 4);
    const float* __restrict__ ub = u + (ov - 1) * NBIT + (q << 4);   /* valid iff ov */
    const float* __restrict__ uU = U + (q << 4) * NTRAIN + j;
    bool own0 = (q == 0), own1 = (q == 1), own2 = (q == 2), own3 = (q == 3);
    float uv;
    PRELD(0)  PRELD(1)  PRELD(2)  PRELD(3)
    PRELD(4)  PRELD(5)  PRELD(6)  PRELD(7)
    PRELD(8)  PRELD(9)  PRELD(10) PRELD(11)
    PRELD(12) PRELD(13) PRELD(14) PRELD(15)

    LSTEP(0,0,0)   LSTEP(1,1,0)   LSTEP(2,2,0)   LSTEP(3,3,0)
    LSTEP(4,4,0)   LSTEP(5,5,0)   LSTEP(6,6,0)   LSTEP(7,7,0)
    LSTEP(8,8,0)   LSTEP(9,9,0)   LSTEP(10,10,0) LSTEP(11,11,0)
    LSTEP(12,12,0) LSTEP(13,13,0) LSTEP(14,14,0) LSTEP(15,15,0)
    LSTEP(16,0,1)  LSTEP(17,1,1)  LSTEP(18,2,1)  LSTEP(19,3,1)
    LSTEP(20,4,1)  LSTEP(21,5,1)  LSTEP(22,6,1)  LSTEP(23,7,1)
    LSTEP(24,8,1)  LSTEP(25,9,1)  LSTEP(26,10,1) LSTEP(27,11,1)
    LSTEP(28,12,1) LSTEP(29,13,1) LSTEP(30,14,1) LSTEP(31,15,1)
    LSTEP(32,0,2)  LSTEP(33,1,2)  LSTEP(34,2,2)  LSTEP(35,3,2)
    LSTEP(36,4,2)  LSTEP(37,5,2)  LSTEP(38,6,2)  LSTEP(39,7,2)
    LSTEP(40,8,2)  LSTEP(41,9,2)  LSTEP(42,10,2) LSTEP(43,11,2)
    LSTEP(44,12,2) LSTEP(45,13,2) LSTEP(46,14,2) LSTEP(47,15,2)
    LSTEP(48,0,3)  LSTEP(49,1,3)  LSTEP(50,2,3)  LSTEP(51,3,3)
    LSTEP(52,4,3)  LSTEP(53,5,3)  LSTEP(54,6,3)  LSTEP(55,7,3)
    LSTEP(56,8,3)  LSTEP(57,9,3)  LSTEP(58,10,3) LSTEP(59,11,3)
    LSTEP(60,12,3) LSTEP(61,13,3) LSTEP(62,14,3) LSTEP(63,15,3)

    u32 ch = 0u;
    OUTB(0)  OUTB(1)  OUTB(2)  OUTB(3)
    OUTB(4)  OUTB(5)  OUTB(6)  OUTB(7)
    OUTB(8)  OUTB(9)  OUTB(10) OUTB(11)
    OUTB(12) OUTB(13) OUTB(14) OUTB(15)
    u64 part = ((u64)ch) << (q << 4);
    part |= __shfl_xor(part, 1, 64);
    part |= __shfl_xor(part, 2, 64);
    if (q == 0) Bmask[j] = part;
}

// likelihood: thread-per-column; U column in regs, u rows via uniform loads
__global__ __launch_bounds__(256) void k_lik(const float* __restrict__ U,
                                             const float* __restrict__ u,
                                             const int* __restrict__ labelY,
                                             const int* __restrict__ ovr,
                                             const int* __restrict__ ylab,
                                             float* __restrict__ partials) {
    __shared__ float sbuf[8];
    int j = blockIdx.x * 256 + threadIdx.x;
    float acc = 0.0f;
    if (j < NTRAIN) {
        int ov = ovr[j];
        const float* up; int ustr;
        if (ov) { up = u + (ov - 1) * NBIT; ustr = 1; }
        else    { up = U + j;               ustr = NTRAIN; }
        float Ucol[NBIT];
        #pragma unroll
        for (int i = 0; i < NBIT; ++i) Ucol[i] = up[i * ustr];
        int cj = labelY[j];
        for (int b = 0; b < NBATCH; ++b) {
            const float* ub = u + b * NBIT;
            float a0 = 0, a1 = 0, a2 = 0, a3 = 0;
            #pragma unroll
            for (int i = 0; i < NBIT; i += 4) {
                a0 = fmaf(ub[i],     Ucol[i],     a0);
                a1 = fmaf(ub[i + 1], Ucol[i + 1], a1);
                a2 = fmaf(ub[i + 2], Ucol[i + 2], a2);
                a3 = fmaf(ub[i + 3], Ucol[i + 3], a3);
            }
            float ip = 0.5f * ((a0 + a1) + (a2 + a3));
            float aip = fabsf(ip);
            float t = __logf(1.0f + __expf(-aip)) + fmaxf(ip, 0.0f);
            if (ylab[b] == cj) t -= ip;
            acc += t;
        }
    }
    float tot = blk_reduce_sum(acc, sbuf);
    if (threadIdx.x == 0) partials[blockIdx.x] = tot;
}

// fused: cl/reg losses + final combine
__global__ void k_clfin(const float* __restrict__ Wg,
                        const u64* __restrict__ Bmask,
                        const int* __restrict__ ind,
                        const float* __restrict__ y,
                        const float* __restrict__ partials,
                        float* __restrict__ out) {
    __shared__ float sbuf[8];
    __shared__ u64 mB[NBATCH];
    int tid = threadIdx.x;
    if (tid < NBATCH) mB[tid] = Bmask[ind[tid]];
    __syncthreads();
    float accCl = 0.f;
    for (int e = tid; e < NCLASS * NBATCH; e += 256) {
        int b = e & 127, c = e >> 7;
        u64 m = mB[b];
        float d0 = 0.f;
        #pragma unroll
        for (int i = 0; i < NBIT; ++i) {
            float w = Wg[i * NCLASS + c];
            d0 += ((m >> i) & 1ull) ? w : -w;
        }
        float diff = y[b * NCLASS + c] - d0;
        accCl = fmaf(diff, diff, accCl);
    }
    float accRg = 0.f;
    for (int e = tid; e < NBIT * NCLASS; e += 256) {
        float w = Wg[e];
        accRg = fmaf(w, w, accRg);
    }
    float a = 0.f;
    for (int i = tid; i < NBLK; i += 256) a += partials[i];
    float clS  = blk_reduce_sum(accCl, sbuf);
    float rgS  = blk_reduce_sum(accRg, sbuf);
    float lik  = blk_reduce_sum(a, sbuf);
    if (tid == 0) {
        out[0] = lik * (1.0f / ((float)NBATCH * (float)NTRAIN))
               + clS * (1.0f / (float)(NCLASS * NBATCH))
               + rgS * (1.0f / (float)(NBIT * NCLASS));
    }
}

extern "C" void kernel_launch(void* const* d_in, const int* in_sizes, int n_in,
                              void* d_out, int out_size, void* d_ws, size_t ws_size,
                              hipStream_t stream) {
    const float* u   = (const float*)d_in[0];
    const float* y   = (const float*)d_in[1];
    const float* U   = (const float*)d_in[2];
    const float* B   = (const float*)d_in[3];
    const float* Y   = (const float*)d_in[4];
    const int*   ind = (const int*)d_in[5];

    char* ws = (char*)d_ws;
    u64*   Bmask  = (u64*)(ws + OFF_BMASK);
    u64*   planes = (u64*)(ws + OFF_PLANES);
    u64*   cmask  = (u64*)(ws + OFF_CMASK);
    int*   labelY = (int*)(ws + OFF_LABELY);
    int*   ovr    = (int*)(ws + OFF_OVR);
    int*   ylab   = (int*)(ws + OFF_YLAB);
    int*   ccount = (int*)(ws + OFF_CCOUNT);
    float* W      = (float*)(ws + OFF_W);
    float* G      = (float*)(ws + OFF_G);
    float* part   = (float*)(ws + OFF_PART);
    int*   iA     = (int*)(ws + OFF_IA);
    int*   iB     = (int*)(ws + OFF_IB);
    float* WT     = (float*)(ws + OFF_WT);

    hipMemsetAsync(ovr,   0, NTRAIN * sizeof(int), stream);
    hipMemsetAsync(cmask, 0, (size_t)NCLASS * NWP * sizeof(u64), stream);
    hipMemsetAsync(iA,    0, (4096 + 6400) * sizeof(int), stream);

    k_scatter<<<1, 128, 0, stream>>>(y, ind, ovr, ylab);
    k_prep   <<<NBLK, 256, 0, stream>>>(Y, B, ovr, ylab, labelY, Bmask, cmask);
    k_counts <<<NCLASS, 256, 0, stream>>>(cmask, ccount);

    for (int pass = 0; pass < 3; ++pass) {
        k_transpose<<<NBLK, 256, 0, stream>>>(Bmask, planes);
        k_bbt2     <<<NCHUNK, 256, 0, stream>>>(planes, cmask, iA, iB);
        k_solve    <<<1, 1024, 0, stream>>>(iA, iB, ccount, iA, iB, W, WT, G);
        k_scan4    <<<NBLK4, 256, 0, stream>>>(Bmask, labelY, ovr, WT, G, U, u);
    }

    k_lik  <<<NBLK, 256, 0, stream>>>(U, u, labelY, ovr, ylab, part);
    k_clfin<<<1, 256, 0, stream>>>(W, Bmask, ind, y, part, (float*)d_out);
}

// Round 5
// 492.567 us; speedup vs baseline: 3.7634x; 1.2936x over previous
//
#include <hip/hip_runtime.h>
#include <hip/hip_bf16.h>

#define NTRAIN 100000
#define NBIT   64
#define NCLASS 100
#define NBATCH 128
#define NW     1563   /* ceil(100000/64) */
#define NWP    1568   /* padded stride   */
#define NP1    100001.0f
#define ETA_MU 55.0f

#define NBLK   391    /* ceil(100000/256) */
#define NBLK4  1563   /* ceil(100000*4/256): 4 lanes per column */
#define CCH    32     /* words per k_bbt3 chunk */
#define NCHUNK 49     /* ceil(NW/CCH) -> 49*32 = 1568 */
#define GSTR   68     /* padded LDS stride for G rows */

typedef unsigned long long u64;
typedef unsigned int u32;

// ---------------- workspace layout (bytes) ----------------
#define OFF_BMASK   0u                       /* u64[100000]      800000 */
#define OFF_CMASK   1602816u                 /* u64[100][1568]  1254400 */
#define OFF_LABELY  2857216u                 /* int[100000]      400000 */
#define OFF_OVR     3257216u                 /* int[100000]      400000 */
#define OFF_YLAB    3657216u                 /* int[128]            512 */
#define OFF_CCOUNT  3657728u                 /* int[100]            512 */
#define OFF_W       3700224u                 /* f32[64][100]      25600 */
#define OFF_G       3725824u                 /* f32[64][64]       16384 */
#define OFF_PART    3742208u                 /* f32[391]                */
#define OFF_IA      3744512u                 /* int[4096]         16384 */
#define OFF_IB      3760896u                 /* int[6400]         25600 */
#define OFF_WT      3786496u                 /* f32[100][64]      25600 */

__device__ __forceinline__ float blk_reduce_sum(float v, float* sbuf) {
    int tid = threadIdx.x;
    for (int off = 32; off > 0; off >>= 1) v += __shfl_down(v, off, 64);
    __syncthreads();
    if ((tid & 63) == 0) sbuf[tid >> 6] = v;
    __syncthreads();
    float t = 0.f;
    if (tid == 0) {
        int nw = (int)(blockDim.x >> 6);
        for (int q = 0; q < nw; ++q) t += sbuf[q];
    }
    return t;   // valid on tid 0 only
}

// batch labels + sequential (last-wins) override table (runs FIRST)
__global__ void k_scatter(const float* __restrict__ y, const int* __restrict__ ind,
                          int* __restrict__ ovr, int* __restrict__ ylab) {
    __shared__ int cls[NBATCH], idx[NBATCH];
    int k = threadIdx.x;
    if (k < NBATCH) {
        int c = 0;
        for (int r = 0; r < NCLASS; ++r)
            if (y[k * NCLASS + r] > 0.5f) c = r;
        cls[k] = c; idx[k] = ind[k]; ylab[k] = c;
    }
    __syncthreads();
    if (k == 0) {
        for (int q = 0; q < NBATCH; ++q) ovr[idx[q]] = q + 1;
    }
}

// fused: final label per column (Y or override), B sign-mask, class bitmask
__global__ __launch_bounds__(256) void k_prep(const float* __restrict__ Y,
                                              const float* __restrict__ B,
                                              const int* __restrict__ ovr,
                                              const int* __restrict__ ylab,
                                              int* __restrict__ labelY,
                                              u64* __restrict__ Bmask,
                                              u64* __restrict__ cmask) {
    int j = blockIdx.x * 256 + threadIdx.x;
    if (j >= NTRAIN) return;
    int lab = 0;
    for (int r = 0; r < NCLASS; ++r)
        if (Y[r * NTRAIN + j] > 0.5f) lab = r;
    int ov = ovr[j];
    if (ov) lab = ylab[ov - 1];
    labelY[j] = lab;
    u64 m = 0ull;
    #pragma unroll
    for (int i = 0; i < NBIT; ++i)
        if (B[i * NTRAIN + j] > 0.0f) m |= (1ull << i);
    Bmask[j] = m;
    atomicOr(&cmask[(size_t)lab * NWP + (j >> 6)], 1ull << (j & 63));
}

// class sizes: one block per class, coalesced word-strided popcount
__global__ __launch_bounds__(256) void k_counts(const u64* __restrict__ cmask,
                                                int* __restrict__ ccount) {
    __shared__ int sb[4];
    int c = blockIdx.x, tid = threadIdx.x;
    int cnt = 0;
    for (int w = tid; w < NW; w += 256) cnt += __popcll(cmask[(size_t)c * NWP + w]);
    for (int off = 32; off > 0; off >>= 1) cnt += __shfl_down(cnt, off, 64);
    if ((tid & 63) == 0) sb[tid >> 6] = cnt;
    __syncthreads();
    if (tid == 0) ccount[c] = sb[0] + sb[1] + sb[2] + sb[3];
}

// fused ballot-transpose + chunked BB^T / BY^T.
// Block owns 32 plane words (2048 columns); transposes Bmask in-LDS (planes
// never hit global), then XOR/AND-popcounts into int atomics (deterministic).
__global__ __launch_bounds__(256) void k_bbt3(const u64* __restrict__ Bmask,
                                              const u64* __restrict__ cmask,
                                              int* __restrict__ iA,
                                              int* __restrict__ iB) {
    __shared__ u64 Lp[64 * 33];
    __shared__ u64 Lc[100 * 33];
    int tid = threadIdx.x, lane = tid & 63, wid = tid >> 6;
    int w0 = blockIdx.x * CCH;
    for (int idx = tid; idx < 100 * CCH; idx += 256) {
        int r = idx >> 5, w = idx & 31;
        int gw = w0 + w;
        Lc[r * 33 + w] = (gw < NW) ? cmask[(size_t)r * NWP + gw] : 0ull;
    }
    // ballot-transpose: wave wid handles words wid*8 .. wid*8+7
    for (int rr = 0; rr < 8; ++rr) {
        int w = wid * 8 + rr;
        int j = (w0 + w) * 64 + lane;
        u64 m = (j < NTRAIN) ? Bmask[j] : 0ull;
        u64 acc = 0ull;
        #pragma unroll
        for (int i = 0; i < 64; ++i) {
            u64 bal = __ballot((m >> i) & 1ull);
            if (lane == i) acc = bal;
        }
        Lp[lane * 33 + w] = acc;
    }
    __syncthreads();
    int k = lane, grp = wid;
    int cntA[16], cntB[25];
    #pragma unroll
    for (int i = 0; i < 16; ++i) cntA[i] = 0;
    #pragma unroll
    for (int i = 0; i < 25; ++i) cntB[i] = 0;
    for (int w = 0; w < CCH; ++w) {
        u64 pkw = Lp[k * 33 + w];
        #pragma unroll
        for (int li = 0; li < 16; ++li)
            cntA[li] += __popcll(pkw ^ Lp[(grp + 4 * li) * 33 + w]);
        #pragma unroll
        for (int ci = 0; ci < 25; ++ci)
            cntB[ci] += __popcll(pkw & Lc[(grp * 25 + ci) * 33 + w]);
    }
    #pragma unroll
    for (int li = 0; li < 16; ++li)
        atomicAdd(&iA[k * 64 + grp + 4 * li], cntA[li]);
    #pragma unroll
    for (int ci = 0; ci < 25; ++ci)
        atomicAdd(&iB[k * 100 + grp * 25 + ci], cntB[ci]);
}

// per-column Neumann solve: x <- v - A x (4 matvecs, ||A||~0.05 -> err ~3e-7).
// 25 blocks x 4 waves; wave = one class column. A staged in LDS (pad 65:
// bank (lane+k)%32 -> conflict-free).
__global__ __launch_bounds__(256) void k_wsolve(const int* __restrict__ iA_g,
                                                const int* __restrict__ iB_g,
                                                const int* __restrict__ ccount,
                                                float* __restrict__ W_g,
                                                float* __restrict__ WT_g) {
    __shared__ float As[64 * 65];
    __shared__ float xb[4][64];
    int tid = threadIdx.x, lane = tid & 63, wid = tid >> 6;
    for (int e = tid; e < 4096; e += 256) {
        int r = e >> 6, k = e & 63;
        As[r * 65 + k] = (r == k) ? 0.0f
                                  : (float)(NTRAIN - 2 * iA_g[e]) * (1.0f / NP1);
    }
    int c = blockIdx.x * 4 + wid;
    float v = (float)(2 * iB_g[lane * 100 + c] - ccount[c]);
    float x = v;
    __syncthreads();
    for (int it = 0; it < 4; ++it) {
        xb[wid][lane] = x;
        __syncthreads();
        const float* __restrict__ Ar = As + lane * 65;
        const float* __restrict__ xv = xb[wid];
        float a0 = 0, a1 = 0, a2 = 0, a3 = 0;
        #pragma unroll 8
        for (int k = 0; k < 64; k += 4) {
            a0 = fmaf(Ar[k],     xv[k],     a0);
            a1 = fmaf(Ar[k + 1], xv[k + 1], a1);
            a2 = fmaf(Ar[k + 2], xv[k + 2], a2);
            a3 = fmaf(Ar[k + 3], xv[k + 3], a3);
        }
        x = v - ((a0 + a1) + (a2 + a3));
        __syncthreads();
    }
    float w = x * (1.0f / NP1);
    W_g[lane * 100 + c] = w;
    WT_g[c * 64 + lane] = w;
}

// G = W W^T (zero diag) from WT; also zeroes iA/iB for the next pass's atomics
__global__ __launch_bounds__(256) void k_gram(const float* __restrict__ WT,
                                              float* __restrict__ G_g,
                                              int* __restrict__ iA_z,
                                              int* __restrict__ iB_z) {
    __shared__ float WTs[6400];
    int tid = threadIdx.x;
    for (int e = tid; e < 6400; e += 256) WTs[e] = WT[e];
    __syncthreads();
    int e = blockIdx.x * 256 + tid;
    int k = e >> 6, l = e & 63;
    float a0 = 0, a1 = 0;
    #pragma unroll 10
    for (int c = 0; c < 100; c += 2) {
        a0 = fmaf(WTs[c * 64 + k],       WTs[c * 64 + l],       a0);
        a1 = fmaf(WTs[(c + 1) * 64 + k], WTs[(c + 1) * 64 + l], a1);
    }
    G_g[e] = (k == l) ? 0.0f : (a0 + a1);
    iA_z[e] = 0;
    for (int z = e; z < 6400; z += 4096) iB_z[z] = 0;
}

// ---------------- quad-split DCC scan ----------------
#define PRELD(t) \
    uv = ov ? ub[t] : uU[(t) * NTRAIN]; \
    float p##t = fmaf(ETA_MU, uv, wq[t]); \
    float s##t = ((mq >> (t)) & 1u) ? 1.0f : -1.0f;

#define LSTEP(i, X, Q) { \
    const float4* Gr = (const float4*)(Gs + (i) * GSTR + (q << 4)); \
    float4 ga = Gr[0], gb = Gr[1], gc = Gr[2], gd = Gr[3]; \
    float f0 = ga.x * s0, f1 = ga.y * s1, f2 = ga.z * s2, f3 = ga.w * s3; \
    f0 = fmaf(gb.x, s4,  f0); f1 = fmaf(gb.y, s5,  f1); \
    f2 = fmaf(gb.z, s6,  f2); f3 = fmaf(gb.w, s7,  f3); \
    f0 = fmaf(gc.x, s8,  f0); f1 = fmaf(gc.y, s9,  f1); \
    f2 = fmaf(gc.z, s10, f2); f3 = fmaf(gc.w, s11, f3); \
    f0 = fmaf(gd.x, s12, f0); f1 = fmaf(gd.y, s13, f1); \
    f2 = fmaf(gd.z, s14, f2); f3 = fmaf(gd.w, s15, f3); \
    float f = (f0 + f1) + (f2 + f3); \
    f += __shfl_xor(f, 1, 64); \
    f += __shfl_xor(f, 2, 64); \
    float nv = ((p##X - f) > 0.0f) ? 1.0f : -1.0f; \
    s##X = own##Q ? nv : s##X; \
}

#define OUTB(t) ch |= (s##t > 0.0f) ? (1u << (t)) : 0u;

__global__ __launch_bounds__(256) void k_scan4(u64* __restrict__ Bmask,
                                               const int* __restrict__ labelY,
                                               const int* __restrict__ ovr,
                                               const float* __restrict__ WT,
                                               const float* __restrict__ Gg,
                                               const float* __restrict__ U,
                                               const float* __restrict__ u) {
    __shared__ float Gs[64 * GSTR];
    int tid = threadIdx.x;
    for (int e = tid; e < 4096; e += 256)
        Gs[(e >> 6) * GSTR + (e & 63)] = Gg[e];
    __syncthreads();
    int j = blockIdx.x * 64 + (tid >> 2);
    if (j >= NTRAIN) return;
    int q = tid & 3;
    u64 m = Bmask[j];
    int c = labelY[j];
    int ov = ovr[j];
    u32 mq = (u32)(m >> (q << 4));
    const float* __restrict__ wq = WT + c * 64 + (q << 4);
    const float* __restrict__ ub = u + (ov - 1) * NBIT + (q << 4);   /* valid iff ov */
    const float* __restrict__ uU = U + (q << 4) * NTRAIN + j;
    bool own0 = (q == 0), own1 = (q == 1), own2 = (q == 2), own3 = (q == 3);
    float uv;
    PRELD(0)  PRELD(1)  PRELD(2)  PRELD(3)
    PRELD(4)  PRELD(5)  PRELD(6)  PRELD(7)
    PRELD(8)  PRELD(9)  PRELD(10) PRELD(11)
    PRELD(12) PRELD(13) PRELD(14) PRELD(15)

    LSTEP(0,0,0)   LSTEP(1,1,0)   LSTEP(2,2,0)   LSTEP(3,3,0)
    LSTEP(4,4,0)   LSTEP(5,5,0)   LSTEP(6,6,0)   LSTEP(7,7,0)
    LSTEP(8,8,0)   LSTEP(9,9,0)   LSTEP(10,10,0) LSTEP(11,11,0)
    LSTEP(12,12,0) LSTEP(13,13,0) LSTEP(14,14,0) LSTEP(15,15,0)
    LSTEP(16,0,1)  LSTEP(17,1,1)  LSTEP(18,2,1)  LSTEP(19,3,1)
    LSTEP(20,4,1)  LSTEP(21,5,1)  LSTEP(22,6,1)  LSTEP(23,7,1)
    LSTEP(24,8,1)  LSTEP(25,9,1)  LSTEP(26,10,1) LSTEP(27,11,1)
    LSTEP(28,12,1) LSTEP(29,13,1) LSTEP(30,14,1) LSTEP(31,15,1)
    LSTEP(32,0,2)  LSTEP(33,1,2)  LSTEP(34,2,2)  LSTEP(35,3,2)
    LSTEP(36,4,2)  LSTEP(37,5,2)  LSTEP(38,6,2)  LSTEP(39,7,2)
    LSTEP(40,8,2)  LSTEP(41,9,2)  LSTEP(42,10,2) LSTEP(43,11,2)
    LSTEP(44,12,2) LSTEP(45,13,2) LSTEP(46,14,2) LSTEP(47,15,2)
    LSTEP(48,0,3)  LSTEP(49,1,3)  LSTEP(50,2,3)  LSTEP(51,3,3)
    LSTEP(52,4,3)  LSTEP(53,5,3)  LSTEP(54,6,3)  LSTEP(55,7,3)
    LSTEP(56,8,3)  LSTEP(57,9,3)  LSTEP(58,10,3) LSTEP(59,11,3)
    LSTEP(60,12,3) LSTEP(61,13,3) LSTEP(62,14,3) LSTEP(63,15,3)

    u32 ch = 0u;
    OUTB(0)  OUTB(1)  OUTB(2)  OUTB(3)
    OUTB(4)  OUTB(5)  OUTB(6)  OUTB(7)
    OUTB(8)  OUTB(9)  OUTB(10) OUTB(11)
    OUTB(12) OUTB(13) OUTB(14) OUTB(15)
    u64 part = ((u64)ch) << (q << 4);
    part |= __shfl_xor(part, 1, 64);
    part |= __shfl_xor(part, 2, 64);
    if (q == 0) Bmask[j] = part;
}

// likelihood: thread-per-column; U column in regs, u rows via uniform loads
__global__ __launch_bounds__(256) void k_lik(const float* __restrict__ U,
                                             const float* __restrict__ u,
                                             const int* __restrict__ labelY,
                                             const int* __restrict__ ovr,
                                             const int* __restrict__ ylab,
                                             float* __restrict__ partials) {
    __shared__ float sbuf[8];
    int j = blockIdx.x * 256 + threadIdx.x;
    float acc = 0.0f;
    if (j < NTRAIN) {
        int ov = ovr[j];
        const float* up; int ustr;
        if (ov) { up = u + (ov - 1) * NBIT; ustr = 1; }
        else    { up = U + j;               ustr = NTRAIN; }
        float Ucol[NBIT];
        #pragma unroll
        for (int i = 0; i < NBIT; ++i) Ucol[i] = up[i * ustr];
        int cj = labelY[j];
        for (int b = 0; b < NBATCH; ++b) {
            const float* ub = u + b * NBIT;
            float a0 = 0, a1 = 0, a2 = 0, a3 = 0;
            #pragma unroll
            for (int i = 0; i < NBIT; i += 4) {
                a0 = fmaf(ub[i],     Ucol[i],     a0);
                a1 = fmaf(ub[i + 1], Ucol[i + 1], a1);
                a2 = fmaf(ub[i + 2], Ucol[i + 2], a2);
                a3 = fmaf(ub[i + 3], Ucol[i + 3], a3);
            }
            float ip = 0.5f * ((a0 + a1) + (a2 + a3));
            float aip = fabsf(ip);
            float t = __logf(1.0f + __expf(-aip)) + fmaxf(ip, 0.0f);
            if (ylab[b] == cj) t -= ip;
            acc += t;
        }
    }
    float tot = blk_reduce_sum(acc, sbuf);
    if (threadIdx.x == 0) partials[blockIdx.x] = tot;
}

// fused: cl/reg losses + final combine
__global__ void k_clfin(const float* __restrict__ Wg,
                        const u64* __restrict__ Bmask,
                        const int* __restrict__ ind,
                        const float* __restrict__ y,
                        const float* __restrict__ partials,
                        float* __restrict__ out) {
    __shared__ float sbuf[8];
    __shared__ u64 mB[NBATCH];
    int tid = threadIdx.x;
    if (tid < NBATCH) mB[tid] = Bmask[ind[tid]];
    __syncthreads();
    float accCl = 0.f;
    for (int e = tid; e < NCLASS * NBATCH; e += 256) {
        int b = e & 127, c = e >> 7;
        u64 m = mB[b];
        float d0 = 0.f;
        #pragma unroll
        for (int i = 0; i < NBIT; ++i) {
            float w = Wg[i * NCLASS + c];
            d0 += ((m >> i) & 1ull) ? w : -w;
        }
        float diff = y[b * NCLASS + c] - d0;
        accCl = fmaf(diff, diff, accCl);
    }
    float accRg = 0.f;
    for (int e = tid; e < NBIT * NCLASS; e += 256) {
        float w = Wg[e];
        accRg = fmaf(w, w, accRg);
    }
    float a = 0.f;
    for (int i = tid; i < NBLK; i += 256) a += partials[i];
    float clS  = blk_reduce_sum(accCl, sbuf);
    float rgS  = blk_reduce_sum(accRg, sbuf);
    float lik  = blk_reduce_sum(a, sbuf);
    if (tid == 0) {
        out[0] = lik * (1.0f / ((float)NBATCH * (float)NTRAIN))
               + clS * (1.0f / (float)(NCLASS * NBATCH))
               + rgS * (1.0f / (float)(NBIT * NCLASS));
    }
}

extern "C" void kernel_launch(void* const* d_in, const int* in_sizes, int n_in,
                              void* d_out, int out_size, void* d_ws, size_t ws_size,
                              hipStream_t stream) {
    const float* u   = (const float*)d_in[0];
    const float* y   = (const float*)d_in[1];
    const float* U   = (const float*)d_in[2];
    const float* B   = (const float*)d_in[3];
    const float* Y   = (const float*)d_in[4];
    const int*   ind = (const int*)d_in[5];

    char* ws = (char*)d_ws;
    u64*   Bmask  = (u64*)(ws + OFF_BMASK);
    u64*   cmask  = (u64*)(ws + OFF_CMASK);
    int*   labelY = (int*)(ws + OFF_LABELY);
    int*   ovr    = (int*)(ws + OFF_OVR);
    int*   ylab   = (int*)(ws + OFF_YLAB);
    int*   ccount = (int*)(ws + OFF_CCOUNT);
    float* W      = (float*)(ws + OFF_W);
    float* G      = (float*)(ws + OFF_G);
    float* part   = (float*)(ws + OFF_PART);
    int*   iA     = (int*)(ws + OFF_IA);
    int*   iB     = (int*)(ws + OFF_IB);
    float* WT     = (float*)(ws + OFF_WT);

    hipMemsetAsync(ovr,   0, NTRAIN * sizeof(int), stream);
    hipMemsetAsync(cmask, 0, (size_t)NCLASS * NWP * sizeof(u64), stream);
    hipMemsetAsync(iA,    0, (4096 + 6400) * sizeof(int), stream);

    k_scatter<<<1, 128, 0, stream>>>(y, ind, ovr, ylab);
    k_prep   <<<NBLK, 256, 0, stream>>>(Y, B, ovr, ylab, labelY, Bmask, cmask);
    k_counts <<<NCLASS, 256, 0, stream>>>(cmask, ccount);

    for (int pass = 0; pass < 3; ++pass) {
        k_bbt3   <<<NCHUNK, 256, 0, stream>>>(Bmask, cmask, iA, iB);
        k_wsolve <<<25, 256, 0, stream>>>(iA, iB, ccount, W, WT);
        k_gram   <<<16, 256, 0, stream>>>(WT, G, iA, iB);
        k_scan4  <<<NBLK4, 256, 0, stream>>>(Bmask, labelY, ovr, WT, G, U, u);
    }

    k_lik  <<<NBLK, 256, 0, stream>>>(U, u, labelY, ovr, ylab, part);
    k_clfin<<<1, 256, 0, stream>>>(W, Bmask, ind, y, part, (float*)d_out);
}

// Round 6
// 386.713 us; speedup vs baseline: 4.7936x; 1.2737x over previous
//
#include <hip/hip_runtime.h>
#include <hip/hip_bf16.h>

#define NTRAIN 100000
#define NBIT   64
#define NCLASS 100
#define NBATCH 128
#define NW     1563   /* ceil(100000/64) */
#define NWP    1568   /* padded stride   */
#define NP1    100001.0f
#define ETA_MU 55.0f

#define NBLK   391    /* ceil(100000/256) */
#define NBLK2  782    /* ceil(100000/128): 2 cols per 4-lane quad */
#define CCH    16     /* words per k_bbt4 chunk */
#define NCHUNK 98     /* 98*16 = 1568 >= NW */
#define GSTR   68     /* padded LDS stride for G rows */

typedef unsigned long long u64;
typedef unsigned int u32;
typedef float v2f __attribute__((ext_vector_type(2)));

// ---------------- workspace layout (bytes) ----------------
#define OFF_BMASK   0u                       /* u64[100000]        800000 */
#define OFF_CMASK   800000u                  /* u64[100][1568]    1254400 */
#define OFF_LABELY  2054400u                 /* int[100000]        400000 */
#define OFF_OVR     2454400u                 /* int[100000]        400000 */
#define OFF_YLAB    2854400u                 /* int[128]              512 */
#define OFF_CCOUNT  2854912u                 /* int[100]              512 */
#define OFF_AF      2855424u                 /* f32[4096]           16384 */
#define OFF_RHS     2871808u                 /* f32[100][64]        25600 */
#define OFF_W       2897408u                 /* f32[64][100]        25600 */
#define OFF_WT      2923008u                 /* f32[100][64]        25600 */
#define OFF_G       2948608u                 /* f32[64][64]         16384 */
#define OFF_PART    2964992u                 /* f32[391]             2048 */
#define OFF_PA      2967040u                 /* int[98][4096]     1605632 */
#define OFF_PB      4572672u                 /* int[98][6400]     2508800 */
/* total ~7.08 MB */

__device__ __forceinline__ float blk_reduce_sum(float v, float* sbuf) {
    int tid = threadIdx.x;
    for (int off = 32; off > 0; off >>= 1) v += __shfl_down(v, off, 64);
    __syncthreads();
    if ((tid & 63) == 0) sbuf[tid >> 6] = v;
    __syncthreads();
    float t = 0.f;
    if (tid == 0) {
        int nw = (int)(blockDim.x >> 6);
        for (int q = 0; q < nw; ++q) t += sbuf[q];
    }
    return t;   // valid on tid 0 only
}

// batch labels + sequential (last-wins) override table (runs FIRST)
__global__ void k_scatter(const float* __restrict__ y, const int* __restrict__ ind,
                          int* __restrict__ ovr, int* __restrict__ ylab) {
    __shared__ int cls[NBATCH], idx[NBATCH];
    int k = threadIdx.x;
    if (k < NBATCH) {
        int c = 0;
        for (int r = 0; r < NCLASS; ++r)
            if (y[k * NCLASS + r] > 0.5f) c = r;
        cls[k] = c; idx[k] = ind[k]; ylab[k] = c;
    }
    __syncthreads();
    if (k == 0) {
        for (int q = 0; q < NBATCH; ++q) ovr[idx[q]] = q + 1;
    }
}

// fused: label per column (Y or override), B sign-mask, cmask via wave ballots
// (no atomics, no cmask memset: every word 0..NW-1 is stored exactly once)
__global__ __launch_bounds__(256) void k_prep(const float* __restrict__ Y,
                                              const float* __restrict__ B,
                                              const int* __restrict__ ovr,
                                              const int* __restrict__ ylab,
                                              int* __restrict__ labelY,
                                              u64* __restrict__ Bmask,
                                              u64* __restrict__ cmask) {
    int tid = threadIdx.x, lane = tid & 63, wid = tid >> 6;
    int w = blockIdx.x * 4 + wid;
    int j = w * 64 + lane;
    int lab = -1;
    if (j < NTRAIN) {
        lab = 0;
        for (int r = 0; r < NCLASS; ++r)
            if (Y[r * NTRAIN + j] > 0.5f) lab = r;
        int ov = ovr[j];
        if (ov) lab = ylab[ov - 1];
        labelY[j] = lab;
        u64 m = 0ull;
        #pragma unroll
        for (int i = 0; i < NBIT; ++i)
            if (B[i * NTRAIN + j] > 0.0f) m |= (1ull << i);
        Bmask[j] = m;
    }
    u64 keep0 = 0ull, keep1 = 0ull;
    for (int c = 0; c < NCLASS; ++c) {
        u64 bal = __ballot(lab == c);
        if (lane == c)      keep0 = bal;
        if (lane == c - 64) keep1 = bal;
    }
    if (w < NW) {
        cmask[(size_t)lane * NWP + w] = keep0;
        if (lane < NCLASS - 64) cmask[(size_t)(lane + 64) * NWP + w] = keep1;
    }
}

// class sizes: one block per class, coalesced word-strided popcount
__global__ __launch_bounds__(256) void k_counts(const u64* __restrict__ cmask,
                                                int* __restrict__ ccount) {
    __shared__ int sb[4];
    int c = blockIdx.x, tid = threadIdx.x;
    int cnt = 0;
    for (int w = tid; w < NW; w += 256) cnt += __popcll(cmask[(size_t)c * NWP + w]);
    for (int off = 32; off > 0; off >>= 1) cnt += __shfl_down(cnt, off, 64);
    if ((tid & 63) == 0) sb[tid >> 6] = cnt;
    __syncthreads();
    if (tid == 0) ccount[c] = sb[0] + sb[1] + sb[2] + sb[3];
}

// fused ballot-transpose + chunked BB^T / BY^T -> PLAIN partial stores
__global__ __launch_bounds__(256) void k_bbt4(const u64* __restrict__ Bmask,
                                              const u64* __restrict__ cmask,
                                              int* __restrict__ pA,
                                              int* __restrict__ pB) {
    __shared__ u64 Lp[64 * 17];
    __shared__ u64 Lc[100 * 17];
    int tid = threadIdx.x, lane = tid & 63, wid = tid >> 6;
    int w0 = blockIdx.x * CCH;
    for (int idx = tid; idx < 100 * CCH; idx += 256) {
        int r = idx >> 4, w = idx & 15;
        int gw = w0 + w;
        Lc[r * 17 + w] = (gw < NW) ? cmask[(size_t)r * NWP + gw] : 0ull;
    }
    for (int rr = 0; rr < 4; ++rr) {
        int w = wid * 4 + rr;
        int j = (w0 + w) * 64 + lane;
        u64 m = (j < NTRAIN) ? Bmask[j] : 0ull;
        u64 acc = 0ull;
        #pragma unroll
        for (int i = 0; i < 64; ++i) {
            u64 bal = __ballot((m >> i) & 1ull);
            if (lane == i) acc = bal;
        }
        Lp[lane * 17 + w] = acc;
    }
    __syncthreads();
    int k = lane, grp = wid;
    int cntA[16], cntB[25];
    #pragma unroll
    for (int i = 0; i < 16; ++i) cntA[i] = 0;
    #pragma unroll
    for (int i = 0; i < 25; ++i) cntB[i] = 0;
    for (int w = 0; w < CCH; ++w) {
        u64 pkw = Lp[k * 17 + w];
        #pragma unroll
        for (int li = 0; li < 16; ++li)
            cntA[li] += __popcll(pkw ^ Lp[(grp + 4 * li) * 17 + w]);
        #pragma unroll
        for (int ci = 0; ci < 25; ++ci)
            cntB[ci] += __popcll(pkw & Lc[(grp * 25 + ci) * 17 + w]);
    }
    size_t bA = (size_t)blockIdx.x * 4096;
    size_t bB = (size_t)blockIdx.x * 6400;
    #pragma unroll
    for (int li = 0; li < 16; ++li)
        pA[bA + (size_t)(grp + 4 * li) * 64 + k] = cntA[li];
    #pragma unroll
    for (int ci = 0; ci < 25; ++ci)
        pB[bB + (size_t)(grp * 25 + ci) * 64 + k] = cntB[ci];
}

// reduce partials -> A_f (scaled, zero-diag) and RHS_f[c*64+k] = 2*cnt - ccount
__global__ __launch_bounds__(256) void k_reduce(const int* __restrict__ pA,
                                                const int* __restrict__ pB,
                                                const int* __restrict__ ccount,
                                                float* __restrict__ A_f,
                                                float* __restrict__ RHS_f) {
    int tid = threadIdx.x, blk = blockIdx.x;
    if (blk < 16) {
        int e = blk * 256 + tid;
        int s = 0;
        for (int ch = 0; ch < NCHUNK; ++ch) s += pA[(size_t)ch * 4096 + e];
        A_f[e] = ((e >> 6) == (e & 63)) ? 0.0f
                                        : (float)(NTRAIN - 2 * s) * (1.0f / NP1);
    } else {
        int e = (blk - 16) * 256 + tid;
        int s = 0;
        for (int ch = 0; ch < NCHUNK; ++ch) s += pB[(size_t)ch * 6400 + e];
        RHS_f[e] = (float)(2 * s - ccount[e >> 6]);
    }
}

// per-column Neumann solve: x <- v - A x (4 matvecs, ||A||~0.05)
__global__ __launch_bounds__(256) void k_wsolve(const float* __restrict__ A_f,
                                                const float* __restrict__ RHS_f,
                                                float* __restrict__ W_g,
                                                float* __restrict__ WT_g) {
    __shared__ float As[64 * 65];
    __shared__ float xb[4][64];
    int tid = threadIdx.x, lane = tid & 63, wid = tid >> 6;
    for (int e = tid; e < 4096; e += 256)
        As[(e >> 6) * 65 + (e & 63)] = A_f[e];
    int c = blockIdx.x * 4 + wid;
    float v = RHS_f[c * 64 + lane];
    float x = v;
    __syncthreads();
    for (int it = 0; it < 4; ++it) {
        xb[wid][lane] = x;
        __syncthreads();
        const float* __restrict__ Ar = As + lane * 65;
        const float* __restrict__ xv = xb[wid];
        float a0 = 0, a1 = 0, a2 = 0, a3 = 0;
        #pragma unroll 8
        for (int k = 0; k < 64; k += 4) {
            a0 = fmaf(Ar[k],     xv[k],     a0);
            a1 = fmaf(Ar[k + 1], xv[k + 1], a1);
            a2 = fmaf(Ar[k + 2], xv[k + 2], a2);
            a3 = fmaf(Ar[k + 3], xv[k + 3], a3);
        }
        x = v - ((a0 + a1) + (a2 + a3));
        __syncthreads();
    }
    float w = x * (1.0f / NP1);
    W_g[lane * 100 + c] = w;
    WT_g[c * 64 + lane] = w;
}

// G = W W^T (zero diag) from WT
__global__ __launch_bounds__(256) void k_gram(const float* __restrict__ WT,
                                              float* __restrict__ G_g) {
    __shared__ float WTs[6400];
    int tid = threadIdx.x;
    for (int e = tid; e < 6400; e += 256) WTs[e] = WT[e];
    __syncthreads();
    int e = blockIdx.x * 256 + tid;
    int k = e >> 6, l = e & 63;
    float a0 = 0, a1 = 0;
    #pragma unroll 10
    for (int c = 0; c < 100; c += 2) {
        a0 = fmaf(WTs[c * 64 + k],       WTs[c * 64 + l],       a0);
        a1 = fmaf(WTs[(c + 1) * 64 + k], WTs[(c + 1) * 64 + l], a1);
    }
    G_g[e] = (k == l) ? 0.0f : (a0 + a1);
}

// ---------------- 2-col quad-split DCC scan, packed v2f FMA ----------------
#define SDECL(P, b0, b1) \
    v2f sA##P = { ((mqA >> (b0)) & 1u) ? 1.f : -1.f, ((mqA >> (b1)) & 1u) ? 1.f : -1.f }; \
    v2f sB##P = { ((mqB >> (b0)) & 1u) ? 1.f : -1.f, ((mqB >> (b1)) & 1u) ? 1.f : -1.f };

#define PDECL(t) \
    float pa##t = fmaf(ETA_MU, (ovA ? ubA[t] : uUA[(t) * NTRAIN]), wqA[t]); \
    float pb##t = fmaf(ETA_MU, (ovB ? ubB[t] : uUB[(t) * NTRAIN]), wqB[t]);

#define LS(i, X, P, C, Q) { \
    const float4* Gr = (const float4*)(Gs + (i) * GSTR + (q << 4)); \
    float4 g0 = Gr[0], g1 = Gr[1], g2 = Gr[2], g3 = Gr[3]; \
    v2f w0 = {g0.x, g0.y}, w1 = {g0.z, g0.w}, w2 = {g1.x, g1.y}, w3 = {g1.z, g1.w}; \
    v2f w4 = {g2.x, g2.y}, w5 = {g2.z, g2.w}, w6 = {g3.x, g3.y}, w7 = {g3.z, g3.w}; \
    v2f xA = w0 * sA0;      xA = w1 * sA1 + xA; \
    v2f yA = w2 * sA2;      yA = w3 * sA3 + yA; \
    xA = w4 * sA4 + xA;     yA = w5 * sA5 + yA; \
    xA = w6 * sA6 + xA;     yA = w7 * sA7 + yA; \
    v2f zA = xA + yA;       float fA = zA.x + zA.y; \
    v2f xB = w0 * sB0;      xB = w1 * sB1 + xB; \
    v2f yB = w2 * sB2;      yB = w3 * sB3 + yB; \
    xB = w4 * sB4 + xB;     yB = w5 * sB5 + yB; \
    xB = w6 * sB6 + xB;     yB = w7 * sB7 + yB; \
    v2f zB = xB + yB;       float fB = zB.x + zB.y; \
    fA += __shfl_xor(fA, 1); fA += __shfl_xor(fA, 2); \
    fB += __shfl_xor(fB, 1); fB += __shfl_xor(fB, 2); \
    float nA = ((pa##X - fA) > 0.0f) ? 1.f : -1.f; \
    float nB = ((pb##X - fB) > 0.0f) ? 1.f : -1.f; \
    sA##P.C = own##Q ? nA : sA##P.C; \
    sB##P.C = own##Q ? nB : sB##P.C; \
}

#define LSQ(Q) \
  LS(16*(Q)+0, 0, 0, x, Q)  LS(16*(Q)+1, 1, 0, y, Q)  LS(16*(Q)+2, 2, 1, x, Q)  LS(16*(Q)+3, 3, 1, y, Q) \
  LS(16*(Q)+4, 4, 2, x, Q)  LS(16*(Q)+5, 5, 2, y, Q)  LS(16*(Q)+6, 6, 3, x, Q)  LS(16*(Q)+7, 7, 3, y, Q) \
  LS(16*(Q)+8, 8, 4, x, Q)  LS(16*(Q)+9, 9, 4, y, Q)  LS(16*(Q)+10,10, 5, x, Q) LS(16*(Q)+11,11, 5, y, Q) \
  LS(16*(Q)+12,12, 6, x, Q) LS(16*(Q)+13,13, 6, y, Q) LS(16*(Q)+14,14, 7, x, Q) LS(16*(Q)+15,15, 7, y, Q)

#define OUTP(t, P, C) { \
    chA |= (sA##P.C > 0.f) ? (1u << (t)) : 0u; \
    chB |= (sB##P.C > 0.f) ? (1u << (t)) : 0u; }

__global__ __launch_bounds__(256) void k_scan2(u64* __restrict__ Bmask,
                                               const int* __restrict__ labelY,
                                               const int* __restrict__ ovr,
                                               const float* __restrict__ WT,
                                               const float* __restrict__ Gg,
                                               const float* __restrict__ U,
                                               const float* __restrict__ u) {
    __shared__ float Gs[64 * GSTR];
    int tid = threadIdx.x;
    for (int e = tid; e < 4096; e += 256)
        Gs[(e >> 6) * GSTR + (e & 63)] = Gg[e];
    __syncthreads();
    int q = tid & 3;
    int jA = blockIdx.x * 128 + (tid >> 2) * 2;
    if (jA >= NTRAIN) return;
    int jB = jA + 1;
    u64 mA_ = Bmask[jA], mB_ = Bmask[jB];
    u32 mqA = (u32)(mA_ >> (q << 4));
    u32 mqB = (u32)(mB_ >> (q << 4));
    int cA = labelY[jA], cB = labelY[jB];
    int ovA = ovr[jA],   ovB = ovr[jB];
    const float* __restrict__ wqA = WT + cA * 64 + (q << 4);
    const float* __restrict__ wqB = WT + cB * 64 + (q << 4);
    const float* __restrict__ ubA = u + (ovA - 1) * NBIT + (q << 4);
    const float* __restrict__ ubB = u + (ovB - 1) * NBIT + (q << 4);
    const float* __restrict__ uUA = U + (size_t)(q << 4) * NTRAIN + jA;
    const float* __restrict__ uUB = U + (size_t)(q << 4) * NTRAIN + jB;
    bool own0 = (q == 0), own1 = (q == 1), own2 = (q == 2), own3 = (q == 3);

    SDECL(0, 0, 1)  SDECL(1, 2, 3)  SDECL(2, 4, 5)  SDECL(3, 6, 7)
    SDECL(4, 8, 9)  SDECL(5,10,11)  SDECL(6,12,13)  SDECL(7,14,15)
    PDECL(0)  PDECL(1)  PDECL(2)  PDECL(3)
    PDECL(4)  PDECL(5)  PDECL(6)  PDECL(7)
    PDECL(8)  PDECL(9)  PDECL(10) PDECL(11)
    PDECL(12) PDECL(13) PDECL(14) PDECL(15)

    LSQ(0) LSQ(1) LSQ(2) LSQ(3)

    u32 chA = 0u, chB = 0u;
    OUTP(0, 0, x)  OUTP(1, 0, y)  OUTP(2, 1, x)  OUTP(3, 1, y)
    OUTP(4, 2, x)  OUTP(5, 2, y)  OUTP(6, 3, x)  OUTP(7, 3, y)
    OUTP(8, 4, x)  OUTP(9, 4, y)  OUTP(10,5, x)  OUTP(11,5, y)
    OUTP(12,6, x)  OUTP(13,6, y)  OUTP(14,7, x)  OUTP(15,7, y)

    u64 wAc = ((u64)chA) << (q << 4);
    u64 wBc = ((u64)chB) << (q << 4);
    wAc |= __shfl_xor(wAc, 1); wAc |= __shfl_xor(wAc, 2);
    wBc |= __shfl_xor(wBc, 1); wBc |= __shfl_xor(wBc, 2);
    if (q == 0) { Bmask[jA] = wAc; Bmask[jB] = wBc; }
}

// likelihood: thread-per-column; U column in regs, u rows via uniform loads
__global__ __launch_bounds__(256) void k_lik(const float* __restrict__ U,
                                             const float* __restrict__ u,
                                             const int* __restrict__ labelY,
                                             const int* __restrict__ ovr,
                                             const int* __restrict__ ylab,
                                             float* __restrict__ partials) {
    __shared__ float sbuf[8];
    int j = blockIdx.x * 256 + threadIdx.x;
    float acc = 0.0f;
    if (j < NTRAIN) {
        int ov = ovr[j];
        const float* up; int ustr;
        if (ov) { up = u + (ov - 1) * NBIT; ustr = 1; }
        else    { up = U + j;               ustr = NTRAIN; }
        float Ucol[NBIT];
        #pragma unroll
        for (int i = 0; i < NBIT; ++i) Ucol[i] = up[i * ustr];
        int cj = labelY[j];
        for (int b = 0; b < NBATCH; ++b) {
            const float* ub = u + b * NBIT;
            float a0 = 0, a1 = 0, a2 = 0, a3 = 0;
            #pragma unroll
            for (int i = 0; i < NBIT; i += 4) {
                a0 = fmaf(ub[i],     Ucol[i],     a0);
                a1 = fmaf(ub[i + 1], Ucol[i + 1], a1);
                a2 = fmaf(ub[i + 2], Ucol[i + 2], a2);
                a3 = fmaf(ub[i + 3], Ucol[i + 3], a3);
            }
            float ip = 0.5f * ((a0 + a1) + (a2 + a3));
            float aip = fabsf(ip);
            float t = __logf(1.0f + __expf(-aip)) + fmaxf(ip, 0.0f);
            if (ylab[b] == cj) t -= ip;
            acc += t;
        }
    }
    float tot = blk_reduce_sum(acc, sbuf);
    if (threadIdx.x == 0) partials[blockIdx.x] = tot;
}

// fused: cl/reg losses + final combine
__global__ void k_clfin(const float* __restrict__ Wg,
                        const u64* __restrict__ Bmask,
                        const int* __restrict__ ind,
                        const float* __restrict__ y,
                        const float* __restrict__ partials,
                        float* __restrict__ out) {
    __shared__ float sbuf[8];
    __shared__ u64 mB[NBATCH];
    int tid = threadIdx.x;
    if (tid < NBATCH) mB[tid] = Bmask[ind[tid]];
    __syncthreads();
    float accCl = 0.f;
    for (int e = tid; e < NCLASS * NBATCH; e += 256) {
        int b = e & 127, c = e >> 7;
        u64 m = mB[b];
        float d0 = 0.f;
        #pragma unroll
        for (int i = 0; i < NBIT; ++i) {
            float w = Wg[i * NCLASS + c];
            d0 += ((m >> i) & 1ull) ? w : -w;
        }
        float diff = y[b * NCLASS + c] - d0;
        accCl = fmaf(diff, diff, accCl);
    }
    float accRg = 0.f;
    for (int e = tid; e < NBIT * NCLASS; e += 256) {
        float w = Wg[e];
        accRg = fmaf(w, w, accRg);
    }
    float a = 0.f;
    for (int i = tid; i < NBLK; i += 256) a += partials[i];
    float clS  = blk_reduce_sum(accCl, sbuf);
    float rgS  = blk_reduce_sum(accRg, sbuf);
    float lik  = blk_reduce_sum(a, sbuf);
    if (tid == 0) {
        out[0] = lik * (1.0f / ((float)NBATCH * (float)NTRAIN))
               + clS * (1.0f / (float)(NCLASS * NBATCH))
               + rgS * (1.0f / (float)(NBIT * NCLASS));
    }
}

extern "C" void kernel_launch(void* const* d_in, const int* in_sizes, int n_in,
                              void* d_out, int out_size, void* d_ws, size_t ws_size,
                              hipStream_t stream) {
    const float* u   = (const float*)d_in[0];
    const float* y   = (const float*)d_in[1];
    const float* U   = (const float*)d_in[2];
    const float* B   = (const float*)d_in[3];
    const float* Y   = (const float*)d_in[4];
    const int*   ind = (const int*)d_in[5];

    char* ws = (char*)d_ws;
    u64*   Bmask  = (u64*)(ws + OFF_BMASK);
    u64*   cmask  = (u64*)(ws + OFF_CMASK);
    int*   labelY = (int*)(ws + OFF_LABELY);
    int*   ovr    = (int*)(ws + OFF_OVR);
    int*   ylab   = (int*)(ws + OFF_YLAB);
    int*   ccount = (int*)(ws + OFF_CCOUNT);
    float* A_f    = (float*)(ws + OFF_AF);
    float* RHS_f  = (float*)(ws + OFF_RHS);
    float* W      = (float*)(ws + OFF_W);
    float* WT     = (float*)(ws + OFF_WT);
    float* G      = (float*)(ws + OFF_G);
    float* part   = (float*)(ws + OFF_PART);
    int*   pA     = (int*)(ws + OFF_PA);
    int*   pB     = (int*)(ws + OFF_PB);

    hipMemsetAsync(ovr, 0, NTRAIN * sizeof(int), stream);

    k_scatter<<<1, 128, 0, stream>>>(y, ind, ovr, ylab);
    k_prep   <<<NBLK, 256, 0, stream>>>(Y, B, ovr, ylab, labelY, Bmask, cmask);
    k_counts <<<NCLASS, 256, 0, stream>>>(cmask, ccount);

    for (int pass = 0; pass < 3; ++pass) {
        k_bbt4   <<<NCHUNK, 256, 0, stream>>>(Bmask, cmask, pA, pB);
        k_reduce <<<41, 256, 0, stream>>>(pA, pB, ccount, A_f, RHS_f);
        k_wsolve <<<25, 256, 0, stream>>>(A_f, RHS_f, W, WT);
        k_gram   <<<16, 256, 0, stream>>>(WT, G);
        k_scan2  <<<NBLK2, 256, 0, stream>>>(Bmask, labelY, ovr, WT, G, U, u);
    }

    k_lik  <<<NBLK, 256, 0, stream>>>(U, u, labelY, ovr, ylab, part);
    k_clfin<<<1, 256, 0, stream>>>(W, Bmask, ind, y, part, (float*)d_out);
}